// Round 1
// baseline (3508.215 us; speedup 1.0000x reference)
//
#include <hip/hip_runtime.h>
#include <math.h>

// Problem constants: B=4, T=4096 -> NROWS=16384; D=1024; S=2048; K=8; H=512
#define NROWS 16384
#define DDIM  1024
#define SKEYS 2048
#define KTOP  8
#define HDIM  512

__device__ __forceinline__ float wave_sum(float v) {
#pragma unroll
    for (int off = 32; off > 0; off >>= 1) v += __shfl_xor(v, off, 64);
    return v;
}

__device__ __forceinline__ float gelu_exact(float v) {
    return 0.5f * v * (1.0f + erff(v * 0.7071067811865475f));
}

// kn[s] = mk[s] / max(||mk[s]||, 1e-12)
__global__ __launch_bounds__(256) void knorm_kernel(const float* __restrict__ mk,
                                                    float* __restrict__ kn) {
    int s = blockIdx.x;
    int t = threadIdx.x;
    const float4* row = (const float4*)(mk + (size_t)s * DDIM);
    float4 v = row[t];  // 256 threads * 4 floats = 1024
    float ss = v.x * v.x + v.y * v.y + v.z * v.z + v.w * v.w;
    ss = wave_sum(ss);
    __shared__ float wsum[4];
    if ((t & 63) == 0) wsum[t >> 6] = ss;
    __syncthreads();
    float tot = wsum[0] + wsum[1] + wsum[2] + wsum[3];
    float sc = 1.0f / fmaxf(sqrtf(tot), 1e-12f);
    float4 o = make_float4(v.x * sc, v.y * sc, v.z * sc, v.w * sc);
    ((float4*)(kn + (size_t)s * DDIM))[t] = o;
}

// qinv[n] = 1 / max(||q[n]||, 1e-12); one wave per row
__global__ __launch_bounds__(256) void qinv_kernel(const float* __restrict__ q,
                                                   float* __restrict__ qinv) {
    int wid = threadIdx.x >> 6, lane = threadIdx.x & 63;
    int row = blockIdx.x * 4 + wid;
    const float4* r = (const float4*)(q + (size_t)row * DDIM);
    float ss = 0.f;
#pragma unroll
    for (int i = 0; i < 4; ++i) {
        float4 v = r[lane + 64 * i];
        ss += v.x * v.x + v.y * v.y + v.z * v.z + v.w * v.w;
    }
    ss = wave_sum(ss);
    if (lane == 0) qinv[row] = 1.0f / fmaxf(sqrtf(ss), 1e-12f);
}

// C[m][n] = epi( sum_k A[m][k]*Bm[n][k] (+bias[n]) )
// A is the virtual concat of A0 (cols [0,K0)) and A1 (cols [K0,Ktot)).
// For a plain GEMM pass A1=A0 and K0=Ktot.
// 64x64 tile, BK=16, 4x4 microkernel, transposed LDS staging (float4 reads).
template<int EPI>
__global__ __launch_bounds__(256) void gemm_nt_kernel(
        const float* __restrict__ A0, const float* __restrict__ A1, int K0, int Ktot,
        const float* __restrict__ Bm, const float* __restrict__ bias,
        float* __restrict__ C, int Ncols) {
    __shared__ float As[16][68];  // [k][row], pad 68 to break conflicts
    __shared__ float Bs[16][68];  // [k][col]
    int tid = threadIdx.x;
    int m0 = blockIdx.y * 64;
    int n0 = blockIdx.x * 64;
    int lr = tid >> 2;            // staging row/col 0..63
    int lc = (tid & 3) * 4;       // staging k offset 0,4,8,12
    int rg = tid >> 4;            // 0..15 -> output rows 4*rg..+3
    int cg = tid & 15;            // 0..15 -> output cols 4*cg..+3
    int K1 = Ktot - K0;
    float acc[4][4] = {};
    for (int kk = 0; kk < Ktot; kk += 16) {
        int col = kk + lc;
        float4 av = (col < K0)
            ? *(const float4*)(A0 + (size_t)(m0 + lr) * K0 + col)
            : *(const float4*)(A1 + (size_t)(m0 + lr) * K1 + (col - K0));
        As[lc + 0][lr] = av.x; As[lc + 1][lr] = av.y;
        As[lc + 2][lr] = av.z; As[lc + 3][lr] = av.w;
        float4 bv = *(const float4*)(Bm + (size_t)(n0 + lr) * Ktot + col);
        Bs[lc + 0][lr] = bv.x; Bs[lc + 1][lr] = bv.y;
        Bs[lc + 2][lr] = bv.z; Bs[lc + 3][lr] = bv.w;
        __syncthreads();
#pragma unroll
        for (int k = 0; k < 16; ++k) {
            float4 a = *(const float4*)&As[k][rg * 4];
            float4 b = *(const float4*)&Bs[k][cg * 4];
            acc[0][0] += a.x * b.x; acc[0][1] += a.x * b.y; acc[0][2] += a.x * b.z; acc[0][3] += a.x * b.w;
            acc[1][0] += a.y * b.x; acc[1][1] += a.y * b.y; acc[1][2] += a.y * b.z; acc[1][3] += a.y * b.w;
            acc[2][0] += a.z * b.x; acc[2][1] += a.z * b.y; acc[2][2] += a.z * b.z; acc[2][3] += a.z * b.w;
            acc[3][0] += a.w * b.x; acc[3][1] += a.w * b.y; acc[3][2] += a.w * b.z; acc[3][3] += a.w * b.w;
        }
        __syncthreads();
    }
    int mb = m0 + rg * 4, nb = n0 + cg * 4;
#pragma unroll
    for (int i = 0; i < 4; ++i) {
        float4 o;
        if (EPI == 1) {
            o.x = gelu_exact(acc[i][0] + bias[nb + 0]);
            o.y = gelu_exact(acc[i][1] + bias[nb + 1]);
            o.z = gelu_exact(acc[i][2] + bias[nb + 2]);
            o.w = gelu_exact(acc[i][3] + bias[nb + 3]);
        } else {
            o = make_float4(acc[i][0], acc[i][1], acc[i][2], acc[i][3]);
        }
        *(float4*)(C + (size_t)(mb + i) * Ncols + nb) = o;
    }
}

// sims = (q . kn) with per-row 1/||q|| scaling folded into the final top-8;
// fused running top-8 + softmax. One block = 64 rows, loop S in tiles of 64.
__global__ __launch_bounds__(256) void simstopk_kernel(
        const float* __restrict__ q, const float* __restrict__ kn,
        const float* __restrict__ qinv,
        float* __restrict__ topw, int* __restrict__ topidx) {
    __shared__ float As[16][68];
    __shared__ float Bs[16][68];
    __shared__ float stile[64][68];
    __shared__ float tv[64][KTOP];
    __shared__ int   ti[64][KTOP];
    int tid = threadIdx.x;
    int m0 = blockIdx.x * 64;
    int lr = tid >> 2;
    int lc = (tid & 3) * 4;
    int rg = tid >> 4;
    int cg = tid & 15;
    if (tid < 64) {
#pragma unroll
        for (int k = 0; k < KTOP; ++k) { tv[tid][k] = -1e30f; ti[tid][k] = 0; }
    }
    __syncthreads();
    for (int st = 0; st < SKEYS / 64; ++st) {
        int s0 = st * 64;
        float acc[4][4] = {};
        for (int kk = 0; kk < DDIM; kk += 16) {
            int col = kk + lc;
            float4 av = *(const float4*)(q + (size_t)(m0 + lr) * DDIM + col);
            As[lc + 0][lr] = av.x; As[lc + 1][lr] = av.y;
            As[lc + 2][lr] = av.z; As[lc + 3][lr] = av.w;
            float4 bv = *(const float4*)(kn + (size_t)(s0 + lr) * DDIM + col);
            Bs[lc + 0][lr] = bv.x; Bs[lc + 1][lr] = bv.y;
            Bs[lc + 2][lr] = bv.z; Bs[lc + 3][lr] = bv.w;
            __syncthreads();
#pragma unroll
            for (int k = 0; k < 16; ++k) {
                float4 a = *(const float4*)&As[k][rg * 4];
                float4 b = *(const float4*)&Bs[k][cg * 4];
                acc[0][0] += a.x * b.x; acc[0][1] += a.x * b.y; acc[0][2] += a.x * b.z; acc[0][3] += a.x * b.w;
                acc[1][0] += a.y * b.x; acc[1][1] += a.y * b.y; acc[1][2] += a.y * b.z; acc[1][3] += a.y * b.w;
                acc[2][0] += a.z * b.x; acc[2][1] += a.z * b.y; acc[2][2] += a.z * b.z; acc[2][3] += a.z * b.w;
                acc[3][0] += a.w * b.x; acc[3][1] += a.w * b.y; acc[3][2] += a.w * b.z; acc[3][3] += a.w * b.w;
            }
            __syncthreads();
        }
#pragma unroll
        for (int i = 0; i < 4; ++i)
            *(float4*)&stile[rg * 4 + i][cg * 4] =
                make_float4(acc[i][0], acc[i][1], acc[i][2], acc[i][3]);
        __syncthreads();
        if (tid < 64) {
            // running top-8 merge for row tid (raw scores; scale is monotone)
            float mn = tv[tid][0]; int mni = 0;
#pragma unroll
            for (int k = 1; k < KTOP; ++k)
                if (tv[tid][k] < mn) { mn = tv[tid][k]; mni = k; }
            for (int c = 0; c < 64; ++c) {
                float v = stile[tid][c];
                if (v > mn) {
                    tv[tid][mni] = v; ti[tid][mni] = s0 + c;
                    mn = tv[tid][0]; mni = 0;
#pragma unroll
                    for (int k = 1; k < KTOP; ++k)
                        if (tv[tid][k] < mn) { mn = tv[tid][k]; mni = k; }
                }
            }
        }
        __syncthreads();
    }
    if (tid < 64) {
        float qs = qinv[m0 + tid];
        float vals[KTOP];
        float m = -1e30f;
#pragma unroll
        for (int k = 0; k < KTOP; ++k) { vals[k] = tv[tid][k] * qs; m = fmaxf(m, vals[k]); }
        float sum = 0.f;
#pragma unroll
        for (int k = 0; k < KTOP; ++k) { vals[k] = expf(vals[k] - m); sum += vals[k]; }
        float inv = 1.0f / sum;
#pragma unroll
        for (int k = 0; k < KTOP; ++k) {
            topw[(size_t)(m0 + tid) * KTOP + k] = vals[k] * inv;
            topidx[(size_t)(m0 + tid) * KTOP + k] = ti[tid][k];
        }
    }
}

// retrieved[row] = sum_k w_k * mv[idx_k]
__global__ __launch_bounds__(256) void retrieve_kernel(
        const float* __restrict__ mv, const float* __restrict__ topw,
        const int* __restrict__ topidx, float* __restrict__ ret) {
    int row = blockIdx.x;
    int t = threadIdx.x;
    __shared__ float w[KTOP];
    __shared__ int   id[KTOP];
    if (t < KTOP) { w[t] = topw[(size_t)row * KTOP + t]; id[t] = topidx[(size_t)row * KTOP + t]; }
    __syncthreads();
    float4 acc = make_float4(0.f, 0.f, 0.f, 0.f);
#pragma unroll
    for (int k = 0; k < KTOP; ++k) {
        float4 v = ((const float4*)(mv + (size_t)id[k] * DDIM))[t];
        float wk = w[k];
        acc.x += wk * v.x; acc.y += wk * v.y; acc.z += wk * v.z; acc.w += wk * v.w;
    }
    ((float4*)(ret + (size_t)row * DDIM))[t] = acc;
}

// gate = sigmoid(h . gW2 + gb2); out = x + gate * ret2   (ret2 lives in `out`)
__global__ __launch_bounds__(256) void out_kernel(
        const float* __restrict__ x, const float* __restrict__ h,
        const float* __restrict__ gW2, const float* __restrict__ gb2,
        float* __restrict__ out) {
    int row = blockIdx.x, t = threadIdx.x;
    const float* hr = h + (size_t)row * HDIM;
    float p = hr[t] * gW2[t] + hr[t + 256] * gW2[t + 256];
    p = wave_sum(p);
    __shared__ float wsum[4];
    if ((t & 63) == 0) wsum[t >> 6] = p;
    __syncthreads();
    float z = wsum[0] + wsum[1] + wsum[2] + wsum[3] + gb2[0];
    float gate = 1.0f / (1.0f + expf(-z));
    float4 xv = ((const float4*)(x + (size_t)row * DDIM))[t];
    float4 rv = ((float4*)(out + (size_t)row * DDIM))[t];
    float4 o = make_float4(xv.x + gate * rv.x, xv.y + gate * rv.y,
                           xv.z + gate * rv.z, xv.w + gate * rv.w);
    ((float4*)(out + (size_t)row * DDIM))[t] = o;
}

extern "C" void kernel_launch(void* const* d_in, const int* in_sizes, int n_in,
                              void* d_out, int out_size, void* d_ws, size_t ws_size,
                              hipStream_t stream) {
    (void)in_sizes; (void)n_in; (void)out_size; (void)ws_size;
    const float* x   = (const float*)d_in[0];  // [N, D]
    const float* mk  = (const float*)d_in[1];  // [S, D]
    const float* mv  = (const float*)d_in[2];  // [S, D]
    const float* Wq  = (const float*)d_in[3];  // [D, D]
    const float* Wo  = (const float*)d_in[4];  // [D, D]
    const float* gW1 = (const float*)d_in[5];  // [H, 2D]
    const float* gb1 = (const float*)d_in[6];  // [H]
    const float* gW2 = (const float*)d_in[7];  // [1, H]
    const float* gb2 = (const float*)d_in[8];  // [1]
    float* out = (float*)d_out;                // [N, D]

    // workspace layout (~110 MB)
    float* q    = (float*)d_ws;                              // N*D (later reused as retrieved)
    float* kn   = q    + (size_t)NROWS * DDIM;               // S*D
    float* qinv = kn   + (size_t)SKEYS * DDIM;               // N
    float* topw = qinv + NROWS;                              // N*KTOP
    int*   topi = (int*)(topw + (size_t)NROWS * KTOP);       // N*KTOP
    float* h    = (float*)(topi + (size_t)NROWS * KTOP);     // N*H

    knorm_kernel<<<SKEYS, 256, 0, stream>>>(mk, kn);

    // q = x @ Wq^T
    gemm_nt_kernel<0><<<dim3(DDIM / 64, NROWS / 64), 256, 0, stream>>>(
        x, x, DDIM, DDIM, Wq, nullptr, q, DDIM);

    qinv_kernel<<<NROWS / 4, 256, 0, stream>>>(q, qinv);

    simstopk_kernel<<<NROWS / 64, 256, 0, stream>>>(q, kn, qinv, topw, topi);

    // retrieved (reuse q buffer)
    retrieve_kernel<<<NROWS, 256, 0, stream>>>(mv, topw, topi, q);

    // ret2 = retrieved @ Wo^T  -> staged in d_out
    gemm_nt_kernel<0><<<dim3(DDIM / 64, NROWS / 64), 256, 0, stream>>>(
        q, q, DDIM, DDIM, Wo, nullptr, out, DDIM);

    // h = gelu([x | ret2] @ gW1^T + gb1)
    gemm_nt_kernel<1><<<dim3(HDIM / 64, NROWS / 64), 256, 0, stream>>>(
        x, out, DDIM, 2 * DDIM, gW1, gb1, h, HDIM);

    // out = x + sigmoid(h.gW2 + gb2) * ret2
    out_kernel<<<NROWS, 256, 0, stream>>>(x, h, gW2, gb2, out);
}

// Round 2
// 475.706 us; speedup vs baseline: 7.3748x; 7.3748x over previous
//
#include <hip/hip_runtime.h>
#include <math.h>

// B=4, T=4096 -> NROWS=16384; D=1024; S=2048; K=8; H=512
#define NROWS 16384
#define DDIM  1024
#define SKEYS 2048
#define KTOP  8
#define HDIM  512

typedef short  s16x8 __attribute__((ext_vector_type(8)));
typedef float  f32x4 __attribute__((ext_vector_type(4)));

#define GL16(g, l) __builtin_amdgcn_global_load_lds(                      \
    (const __attribute__((address_space(1))) void*)(g),                   \
    (__attribute__((address_space(3))) void*)(l), 16, 0, 0)

__device__ __forceinline__ float wave_sum(float v) {
#pragma unroll
    for (int off = 32; off > 0; off >>= 1) v += __shfl_xor(v, off, 64);
    return v;
}

__device__ __forceinline__ unsigned short f2bf(float f) {
    union { float f; unsigned u; } c; c.f = f;
    unsigned u = c.u;
    unsigned r = (u + 0x7FFFu + ((u >> 16) & 1u)) >> 16;
    return (unsigned short)r;
}
__device__ __forceinline__ float bf2f(unsigned short h) {
    union { unsigned u; float f; } c; c.u = ((unsigned)h) << 16;
    return c.f;
}

__device__ __forceinline__ float gelu_exact(float v) {
    return 0.5f * v * (1.0f + erff(v * 0.7071067811865475f));
}

// ---------- fp32 -> bf16 convert (vectorized) ----------
__global__ __launch_bounds__(256) void f2bf_kernel(const float* __restrict__ in,
                                                   unsigned short* __restrict__ out, int n4) {
    for (int i = blockIdx.x * 256 + threadIdx.x; i < n4; i += gridDim.x * 256) {
        float4 v = ((const float4*)in)[i];
        ushort4 o;
        o.x = f2bf(v.x); o.y = f2bf(v.y); o.z = f2bf(v.z); o.w = f2bf(v.w);
        ((ushort4*)out)[i] = o;
    }
}

// ---------- normalize memory_keys, emit bf16 ----------
__global__ __launch_bounds__(256) void knorm_kernel(const float* __restrict__ mk,
                                                    unsigned short* __restrict__ kn) {
    int s = blockIdx.x, t = threadIdx.x;
    float4 v = ((const float4*)(mk + (size_t)s * DDIM))[t];
    float ss = v.x * v.x + v.y * v.y + v.z * v.z + v.w * v.w;
    ss = wave_sum(ss);
    __shared__ float wsum[4];
    if ((t & 63) == 0) wsum[t >> 6] = ss;
    __syncthreads();
    float tot = wsum[0] + wsum[1] + wsum[2] + wsum[3];
    float sc = 1.0f / fmaxf(sqrtf(tot), 1e-12f);
    ushort4 o;
    o.x = f2bf(v.x * sc); o.y = f2bf(v.y * sc); o.z = f2bf(v.z * sc); o.w = f2bf(v.w * sc);
    ((ushort4*)(kn + (size_t)s * DDIM))[t] = o;
}

// ---------- qinv from bf16 q : one wave per row ----------
__global__ __launch_bounds__(256) void qinv_kernel(const unsigned short* __restrict__ qbf,
                                                   float* __restrict__ qinv) {
    int wid = threadIdx.x >> 6, l = threadIdx.x & 63;
    int row = blockIdx.x * 4 + wid;
    const unsigned short* p = qbf + (size_t)row * DDIM + l * 16;
    uint4 a = *(const uint4*)p;
    uint4 b = *(const uint4*)(p + 8);
    float ss = 0.f;
    unsigned wsv[8] = {a.x, a.y, a.z, a.w, b.x, b.y, b.z, b.w};
#pragma unroll
    for (int j = 0; j < 8; ++j) {
        float lo = __uint_as_float(wsv[j] << 16);
        float hi = __uint_as_float(wsv[j] & 0xffff0000u);
        ss += lo * lo + hi * hi;
    }
    ss = wave_sum(ss);
    if (l == 0) qinv[row] = 1.0f / fmaxf(sqrtf(ss), 1e-12f);
}

// ---------- bf16 MFMA GEMM: C[m][n] = sum_k A[m][k] * B[n][k] ----------
// 128x128 tile, 4 waves (2x2 of 64x64), BK=32, global_load_lds(16B) staging,
// ((row&3) XOR) chunk swizzle both sides. A = concat(A0[.,0:K0], A1[.,K0:Ktot]).
template<int EPI, bool OUTF, bool OUTB>
__global__ __launch_bounds__(256) void gemm_bf16(
        const unsigned short* __restrict__ A0, const unsigned short* __restrict__ A1,
        int K0, int Ktot,
        const unsigned short* __restrict__ Bm, const float* __restrict__ bias,
        float* __restrict__ Cf, unsigned short* __restrict__ Cb, int Ncols) {
    __shared__ __align__(16) unsigned short As[128 * 32];
    __shared__ __align__(16) unsigned short Bs[128 * 32];
    int tid = threadIdx.x, l = tid & 63, wid = tid >> 6;
    int m0 = blockIdx.y * 128, n0 = blockIdx.x * 128;
    int wr = wid >> 1, wc = wid & 1;
    int K1 = Ktot - K0;

    f32x4 acc[4][4];
#pragma unroll
    for (int i = 0; i < 4; ++i)
#pragma unroll
        for (int j = 0; j < 4; ++j) acc[i][j] = (f32x4){0.f, 0.f, 0.f, 0.f};

    // staging geometry: thread -> (row = r*64 + wid*16 + (l>>2), chunk = l&3)
    int srow = wid * 16 + (l >> 2);
    int swz  = (l & 3) ^ ((l >> 2) & 3);      // source chunk (XOR swizzle)
    char* aL0 = (char*)As + wid * 1024;
    char* aL1 = (char*)As + 4096 + wid * 1024;
    char* bL0 = (char*)Bs + wid * 1024;
    char* bL1 = (char*)Bs + 4096 + wid * 1024;

    // fragment read geometry
    int frow = (l & 15);
    int fck  = ((l >> 4) ^ (l & 3)) * 16;      // swizzled chunk byte offset

    for (int kk = 0; kk < Ktot; kk += 32) {
        int gk = kk + swz * 8;
        const unsigned short* ga0 = (gk < K0)
            ? A0 + (size_t)(m0 + srow) * K0 + gk
            : A1 + (size_t)(m0 + srow) * K1 + (gk - K0);
        GL16(ga0, aL0);
        const unsigned short* ga1 = (gk < K0)
            ? A0 + (size_t)(m0 + 64 + srow) * K0 + gk
            : A1 + (size_t)(m0 + 64 + srow) * K1 + (gk - K0);
        GL16(ga1, aL1);
        GL16(Bm + (size_t)(n0 + srow) * Ktot + gk, bL0);
        GL16(Bm + (size_t)(n0 + 64 + srow) * Ktot + gk, bL1);
        __syncthreads();

        s16x8 af[4], bfr[4];
#pragma unroll
        for (int mf = 0; mf < 4; ++mf) {
            int ar = wr * 64 + mf * 16 + frow;
            af[mf] = *(const s16x8*)((const char*)As + ar * 64 + fck);
        }
#pragma unroll
        for (int nf = 0; nf < 4; ++nf) {
            int br = wc * 64 + nf * 16 + frow;
            bfr[nf] = *(const s16x8*)((const char*)Bs + br * 64 + fck);
        }
#pragma unroll
        for (int mf = 0; mf < 4; ++mf)
#pragma unroll
            for (int nf = 0; nf < 4; ++nf)
                acc[mf][nf] = __builtin_amdgcn_mfma_f32_16x16x32_bf16(
                    af[mf], bfr[nf], acc[mf][nf], 0, 0, 0);
        __syncthreads();
    }

    // epilogue: D row=(l>>4)*4+reg, col=l&15 (per fragment)
    int crow = (l >> 4) << 2;
    int ccol = l & 15;
#pragma unroll
    for (int mf = 0; mf < 4; ++mf) {
        int gr = m0 + wr * 64 + mf * 16 + crow;
#pragma unroll
        for (int nf = 0; nf < 4; ++nf) {
            int gc = n0 + wc * 64 + nf * 16 + ccol;
            f32x4 v = acc[mf][nf];
#pragma unroll
            for (int r2 = 0; r2 < 4; ++r2) {
                float o = v[r2];
                if (EPI == 1) o = gelu_exact(o + bias[gc]);
                if (OUTF) Cf[(size_t)(gr + r2) * Ncols + gc] = o;
                if (OUTB) Cb[(size_t)(gr + r2) * Ncols + gc] = f2bf(o);
            }
        }
    }
}

// ---------- top-8 + softmax from bf16 sims: one wave per row ----------
#define INS8(v_, i_)                                                     \
    do {                                                                 \
        float cv = (v_); int ci = (i_);                                  \
        _Pragma("unroll")                                                \
        for (int p = 0; p < 8; ++p) {                                    \
            bool sw = cv > val[p];                                       \
            float tv = val[p]; int tix = idx[p];                         \
            val[p] = sw ? cv : val[p];                                   \
            idx[p] = sw ? ci : idx[p];                                   \
            cv = sw ? tv : cv; ci = sw ? tix : ci;                       \
        }                                                                \
    } while (0)

__global__ __launch_bounds__(256) void topk_kernel(
        const unsigned short* __restrict__ sims, const float* __restrict__ qinv,
        float* __restrict__ topw, int* __restrict__ topi) {
    int wid = threadIdx.x >> 6, l = threadIdx.x & 63;
    int row = blockIdx.x * 4 + wid;
    const unsigned short* sr = sims + (size_t)row * SKEYS + l * 32;
    float val[8]; int idx[8];
#pragma unroll
    for (int j = 0; j < 8; ++j) { val[j] = -1e30f; idx[j] = 0; }
#pragma unroll
    for (int c = 0; c < 4; ++c) {
        uint4 raw = *(const uint4*)(sr + c * 8);
        unsigned wsv[4] = {raw.x, raw.y, raw.z, raw.w};
#pragma unroll
        for (int q2 = 0; q2 < 4; ++q2) {
            float lo = __uint_as_float(wsv[q2] << 16);
            float hi = __uint_as_float(wsv[q2] & 0xffff0000u);
            int bi0 = l * 32 + c * 8 + q2 * 2;
            if (lo > val[7]) INS8(lo, bi0);
            if (hi > val[7]) INS8(hi, bi0 + 1);
        }
    }
    // extract global top-8 via 8 rounds of wave argmax
    float ov[8]; int oi[8];
#pragma unroll
    for (int j = 0; j < 8; ++j) {
        float bv = val[0]; int bl = l;
#pragma unroll
        for (int off = 32; off > 0; off >>= 1) {
            float xv = __shfl_xor(bv, off, 64);
            int   xl = __shfl_xor(bl, off, 64);
            if (xv > bv || (xv == bv && xl < bl)) { bv = xv; bl = xl; }
        }
        int bi = __shfl(idx[0], bl, 64);
        ov[j] = bv; oi[j] = bi;
        if (l == bl) {
#pragma unroll
            for (int p = 0; p < 7; ++p) { val[p] = val[p + 1]; idx[p] = idx[p + 1]; }
            val[7] = -1e30f;
        }
    }
    if (l == 0) {
        float qs = qinv[row];
        float m = ov[0] * qs;
        float e[8], ssum = 0.f;
#pragma unroll
        for (int j = 0; j < 8; ++j) { e[j] = expf(ov[j] * qs - m); ssum += e[j]; }
        float inv = 1.0f / ssum;
#pragma unroll
        for (int j = 0; j < 8; ++j) {
            topw[(size_t)row * KTOP + j] = e[j] * inv;
            topi[(size_t)row * KTOP + j] = oi[j];
        }
    }
}

// ---------- retrieved = sum_k w_k * mv[idx_k]  -> bf16 ----------
__global__ __launch_bounds__(256) void retrieve_kernel(
        const float* __restrict__ mv, const float* __restrict__ topw,
        const int* __restrict__ topidx, unsigned short* __restrict__ ret) {
    int row = blockIdx.x, t = threadIdx.x;
    __shared__ float w[KTOP];
    __shared__ int   id[KTOP];
    if (t < KTOP) { w[t] = topw[(size_t)row * KTOP + t]; id[t] = topidx[(size_t)row * KTOP + t]; }
    __syncthreads();
    float4 acc = make_float4(0.f, 0.f, 0.f, 0.f);
#pragma unroll
    for (int k = 0; k < KTOP; ++k) {
        float4 v = ((const float4*)(mv + (size_t)id[k] * DDIM))[t];
        float wk = w[k];
        acc.x += wk * v.x; acc.y += wk * v.y; acc.z += wk * v.z; acc.w += wk * v.w;
    }
    ushort4 o;
    o.x = f2bf(acc.x); o.y = f2bf(acc.y); o.z = f2bf(acc.z); o.w = f2bf(acc.w);
    ((ushort4*)(ret + (size_t)row * DDIM))[t] = o;
}

// ---------- gate + residual ----------
__global__ __launch_bounds__(256) void out_kernel(
        const float* __restrict__ x, const float* __restrict__ h,
        const float* __restrict__ gW2, const float* __restrict__ gb2,
        float* __restrict__ out) {
    int row = blockIdx.x, t = threadIdx.x;
    const float* hr = h + (size_t)row * HDIM;
    float p = hr[t] * gW2[t] + hr[t + 256] * gW2[t + 256];
    p = wave_sum(p);
    __shared__ float wsum[4];
    if ((t & 63) == 0) wsum[t >> 6] = p;
    __syncthreads();
    float z = wsum[0] + wsum[1] + wsum[2] + wsum[3] + gb2[0];
    float gate = 1.0f / (1.0f + expf(-z));
    float4 xv = ((const float4*)(x + (size_t)row * DDIM))[t];
    float4 rv = ((float4*)(out + (size_t)row * DDIM))[t];
    float4 o = make_float4(xv.x + gate * rv.x, xv.y + gate * rv.y,
                           xv.z + gate * rv.z, xv.w + gate * rv.w);
    ((float4*)(out + (size_t)row * DDIM))[t] = o;
}

extern "C" void kernel_launch(void* const* d_in, const int* in_sizes, int n_in,
                              void* d_out, int out_size, void* d_ws, size_t ws_size,
                              hipStream_t stream) {
    (void)in_sizes; (void)n_in; (void)out_size; (void)ws_size;
    const float* x   = (const float*)d_in[0];
    const float* mk  = (const float*)d_in[1];
    const float* mv  = (const float*)d_in[2];
    const float* Wq  = (const float*)d_in[3];
    const float* Wo  = (const float*)d_in[4];
    const float* gW1 = (const float*)d_in[5];
    const float* gb1 = (const float*)d_in[6];
    const float* gW2 = (const float*)d_in[7];
    const float* gb2 = (const float*)d_in[8];
    float* out = (float*)d_out;

    // workspace layout (~180 MB), lifetime-aliased
    char* w = (char*)d_ws;
    unsigned short* x_bf   = (unsigned short*)w;  w += (size_t)NROWS * DDIM * 2;   // 33.5 MB
    unsigned short* qret   = (unsigned short*)w;  w += (size_t)NROWS * DDIM * 2;   // q_bf then ret_bf
    unsigned short* kn_bf  = (unsigned short*)w;  w += (size_t)SKEYS * DDIM * 2;
    unsigned short* wq_bf  = (unsigned short*)w;  w += (size_t)DDIM * DDIM * 2;
    unsigned short* wo_bf  = (unsigned short*)w;  w += (size_t)DDIM * DDIM * 2;
    unsigned short* gw1_bf = (unsigned short*)w;  w += (size_t)HDIM * 2 * DDIM * 2;
    unsigned short* sims   = (unsigned short*)w;  w += (size_t)NROWS * SKEYS * 2;  // later ret2_bf
    float* topw  = (float*)w;                     w += (size_t)NROWS * KTOP * 4;
    int*   topi  = (int*)w;                       w += (size_t)NROWS * KTOP * 4;
    float* qinvb = (float*)w;                     w += (size_t)NROWS * 4;
    float* h     = (float*)w;                     w += (size_t)NROWS * HDIM * 4;
    unsigned short* ret2_bf = sims;               // alias: sims dead after topk

    f2bf_kernel<<<2048, 256, 0, stream>>>(x,   x_bf,   NROWS * DDIM / 4);
    f2bf_kernel<<<512,  256, 0, stream>>>(Wq,  wq_bf,  DDIM * DDIM / 4);
    f2bf_kernel<<<512,  256, 0, stream>>>(Wo,  wo_bf,  DDIM * DDIM / 4);
    f2bf_kernel<<<512,  256, 0, stream>>>(gW1, gw1_bf, HDIM * 2 * DDIM / 4);
    knorm_kernel<<<SKEYS, 256, 0, stream>>>(mk, kn_bf);

    // q_bf = x @ Wq^T (bf16 out only)
    gemm_bf16<0, false, true><<<dim3(DDIM / 128, NROWS / 128), 256, 0, stream>>>(
        x_bf, x_bf, DDIM, DDIM, wq_bf, nullptr, nullptr, qret, DDIM);

    qinv_kernel<<<NROWS / 4, 256, 0, stream>>>(qret, qinvb);

    // sims_bf = q_bf @ kn^T
    gemm_bf16<0, false, true><<<dim3(SKEYS / 128, NROWS / 128), 256, 0, stream>>>(
        qret, qret, DDIM, DDIM, kn_bf, nullptr, nullptr, sims, SKEYS);

    topk_kernel<<<NROWS / 4, 256, 0, stream>>>(sims, qinvb, topw, topi);

    retrieve_kernel<<<NROWS, 256, 0, stream>>>(mv, topw, topi, qret);  // -> ret_bf

    // ret2 = ret @ Wo^T : fp32 -> d_out, bf16 -> ret2_bf
    gemm_bf16<0, true, true><<<dim3(DDIM / 128, NROWS / 128), 256, 0, stream>>>(
        qret, qret, DDIM, DDIM, wo_bf, nullptr, out, ret2_bf, DDIM);

    // h = gelu([x | ret2] @ gW1^T + gb1) : fp32
    gemm_bf16<1, true, false><<<dim3(HDIM / 128, NROWS / 128), 256, 0, stream>>>(
        x_bf, ret2_bf, DDIM, 2 * DDIM, gw1_bf, gb1, h, nullptr, HDIM);

    out_kernel<<<NROWS, 256, 0, stream>>>(x, h, gW2, gb2, out);
}

// Round 3
// 421.059 us; speedup vs baseline: 8.3319x; 1.1298x over previous
//
#include <hip/hip_runtime.h>
#include <math.h>

// B=4, T=4096 -> NROWS=16384; D=1024; S=2048; K=8; H=512
#define NROWS 16384
#define DDIM  1024
#define SKEYS 2048
#define KTOP  8
#define HDIM  512

typedef short  s16x8 __attribute__((ext_vector_type(8)));
typedef float  f32x4 __attribute__((ext_vector_type(4)));

#define GL16(g, l) __builtin_amdgcn_global_load_lds(                      \
    (const __attribute__((address_space(1))) void*)(g),                   \
    (__attribute__((address_space(3))) void*)(l), 16, 0, 0)

__device__ __forceinline__ float wave_sum(float v) {
#pragma unroll
    for (int off = 32; off > 0; off >>= 1) v += __shfl_xor(v, off, 64);
    return v;
}

__device__ __forceinline__ unsigned short f2bf(float f) {
    union { float f; unsigned u; } c; c.f = f;
    unsigned u = c.u;
    unsigned r = (u + 0x7FFFu + ((u >> 16) & 1u)) >> 16;
    return (unsigned short)r;
}
__device__ __forceinline__ float bf2f(unsigned short h) {
    union { unsigned u; float f; } c; c.u = ((unsigned)h) << 16;
    return c.f;
}

__device__ __forceinline__ float gelu_exact(float v) {
    return 0.5f * v * (1.0f + erff(v * 0.7071067811865475f));
}

// ---------- fp32 -> bf16 convert ----------
__global__ __launch_bounds__(256) void f2bf_kernel(const float* __restrict__ in,
                                                   unsigned short* __restrict__ out, int n4) {
    for (int i = blockIdx.x * 256 + threadIdx.x; i < n4; i += gridDim.x * 256) {
        float4 v = ((const float4*)in)[i];
        ushort4 o;
        o.x = f2bf(v.x); o.y = f2bf(v.y); o.z = f2bf(v.z); o.w = f2bf(v.w);
        ((ushort4*)out)[i] = o;
    }
}

// ---------- normalize memory_keys -> bf16 ----------
__global__ __launch_bounds__(256) void knorm_kernel(const float* __restrict__ mk,
                                                    unsigned short* __restrict__ kn) {
    int s = blockIdx.x, t = threadIdx.x;
    float4 v = ((const float4*)(mk + (size_t)s * DDIM))[t];
    float ss = v.x * v.x + v.y * v.y + v.z * v.z + v.w * v.w;
    ss = wave_sum(ss);
    __shared__ float wsum[4];
    if ((t & 63) == 0) wsum[t >> 6] = ss;
    __syncthreads();
    float tot = wsum[0] + wsum[1] + wsum[2] + wsum[3];
    float sc = 1.0f / fmaxf(sqrtf(tot), 1e-12f);
    ushort4 o;
    o.x = f2bf(v.x * sc); o.y = f2bf(v.y * sc); o.z = f2bf(v.z * sc); o.w = f2bf(v.w * sc);
    ((ushort4*)(kn + (size_t)s * DDIM))[t] = o;
}

// ---------- qinv from bf16 q ----------
__global__ __launch_bounds__(256) void qinv_kernel(const unsigned short* __restrict__ qbf,
                                                   float* __restrict__ qinv) {
    int wid = threadIdx.x >> 6, l = threadIdx.x & 63;
    int row = blockIdx.x * 4 + wid;
    const unsigned short* p = qbf + (size_t)row * DDIM + l * 16;
    uint4 a = *(const uint4*)p;
    uint4 b = *(const uint4*)(p + 8);
    float ss = 0.f;
    unsigned wsv[8] = {a.x, a.y, a.z, a.w, b.x, b.y, b.z, b.w};
#pragma unroll
    for (int j = 0; j < 8; ++j) {
        float lo = __uint_as_float(wsv[j] << 16);
        float hi = __uint_as_float(wsv[j] & 0xffff0000u);
        ss += lo * lo + hi * hi;
    }
    ss = wave_sum(ss);
    if (l == 0) qinv[row] = 1.0f / fmaxf(sqrtf(ss), 1e-12f);
}

// ---------- 256x256 bf16 MFMA GEMM, BK=64, 8 waves, dbuf LDS + counted vmcnt ----------
// C[m][n] = epi( sum_k A[m][k]*B[n][k] (+bias) ), A = concat(A0, A1) along k.
// LDS tile [256][64] bf16 (128B rows), swizzle: byte ^= (row&7)<<4, applied
// inverse on the global source (gload_lds dest linear) and on the ds_read side.
template<int EPI, bool OUTF, bool OUTB>
__global__ __launch_bounds__(512, 1) void gemm256(
        const unsigned short* __restrict__ A0, const unsigned short* __restrict__ A1,
        int K0, int Ktot,
        const unsigned short* __restrict__ Bm, const float* __restrict__ bias,
        float* __restrict__ Cf, unsigned short* __restrict__ Cb, int Ncols) {
    __shared__ __align__(16) unsigned short As[2][256 * 64];
    __shared__ __align__(16) unsigned short Bs[2][256 * 64];
    int tid = threadIdx.x, l = tid & 63, wid = tid >> 6;

    // XCD-chunked block swizzle (all grids divisible by 8)
    int gx = gridDim.x;
    int nwg = gx * gridDim.y;
    int bid = blockIdx.y * gx + blockIdx.x;
    int cpx = nwg >> 3;
    int swz = (bid & 7) * cpx + (bid >> 3);
    int m0 = (swz / gx) * 256;
    int n0 = (swz % gx) * 256;

    int wr = wid >> 2, wc = wid & 3;   // 2 (M) x 4 (N) waves; per-wave C = 128x64
    int K1 = Ktot - K0;
    int NT = Ktot >> 6;

    f32x4 acc[8][4];
#pragma unroll
    for (int i = 0; i < 8; ++i)
#pragma unroll
        for (int j = 0; j < 4; ++j) acc[i][j] = (f32x4){0.f, 0.f, 0.f, 0.f};

    // staging geometry: issue i covers rows [i*64, i*64+64); thread -> row, 16B chunk
    int srow   = tid >> 3;                       // 0..63
    int schunk = (tid & 7) ^ (srow & 7);         // inverse-swizzled source chunk
    // per-thread row offsets (element counts), hoisted out of the K loop
    size_t offA0[4], offA1[4], offB[4];
#pragma unroll
    for (int i = 0; i < 4; ++i) {
        size_t ra = (size_t)(m0 + i * 64 + srow);
        offA0[i] = ra * (size_t)K0;
        offA1[i] = ra * (size_t)K1;
        offB[i]  = (size_t)(n0 + i * 64 + srow) * (size_t)Ktot;
    }
    int ldsOff = wid * 512;                      // ushorts; + i*4096 per issue

#define STAGE(bsel, kt_)                                                       \
    do {                                                                       \
        int gk_ = (kt_) * 64 + schunk * 8;                                     \
        _Pragma("unroll")                                                      \
        for (int i_ = 0; i_ < 4; ++i_) {                                       \
            const unsigned short* ga_ = (gk_ < K0)                             \
                ? A0 + offA0[i_] + gk_                                         \
                : A1 + offA1[i_] + (gk_ - K0);                                 \
            GL16(ga_, &As[bsel][i_ * 4096 + ldsOff]);                          \
            GL16(Bm + offB[i_] + gk_, &Bs[bsel][i_ * 4096 + ldsOff]);          \
        }                                                                      \
    } while (0)

    STAGE(0, 0);   // prologue: tile 0 into buf 0 (8 loads in flight)

    for (int kt = 0; kt < NT; ++kt) {
        int b = kt & 1;
        if (kt + 1 < NT) {
            STAGE(b ^ 1, kt + 1);   // 8 more issues -> 16 outstanding
            asm volatile("s_waitcnt vmcnt(8)" ::: "memory");   // prev 8 (this tile) done
        } else {
            asm volatile("s_waitcnt vmcnt(0)" ::: "memory");
        }
        __builtin_amdgcn_s_barrier();          // all waves' stores to buf b landed
        asm volatile("" ::: "memory");

#pragma unroll
        for (int qr = 0; qr < 2; ++qr)
#pragma unroll
        for (int qc = 0; qc < 2; ++qc) {
#pragma unroll
            for (int ks = 0; ks < 2; ++ks) {
                s16x8 af[4], bfr[2];
                int ch = ((ks << 2) + (l >> 4)) ^ (l & 7);   // swizzled 16B chunk
#pragma unroll
                for (int mf = 0; mf < 4; ++mf) {
                    int row = wr * 128 + qr * 64 + mf * 16 + (l & 15);
                    af[mf] = *(const s16x8*)&As[b][row * 64 + ch * 8];
                }
#pragma unroll
                for (int nf = 0; nf < 2; ++nf) {
                    int row = wc * 64 + qc * 32 + nf * 16 + (l & 15);
                    bfr[nf] = *(const s16x8*)&Bs[b][row * 64 + ch * 8];
                }
                __builtin_amdgcn_s_setprio(1);
#pragma unroll
                for (int mf = 0; mf < 4; ++mf)
#pragma unroll
                    for (int nf = 0; nf < 2; ++nf)
                        acc[qr * 4 + mf][qc * 2 + nf] =
                            __builtin_amdgcn_mfma_f32_16x16x32_bf16(
                                af[mf], bfr[nf], acc[qr * 4 + mf][qc * 2 + nf], 0, 0, 0);
                __builtin_amdgcn_s_setprio(0);
            }
            asm volatile("" ::: "memory");
            __builtin_amdgcn_s_barrier();      // quadrant convoy; last one = readers-done
            asm volatile("" ::: "memory");
        }
    }
#undef STAGE

    // epilogue: D row=(l>>4)*4+r2, col=l&15 within each 16x16 fragment
    int crow = (l >> 4) << 2;
    int ccol = l & 15;
#pragma unroll
    for (int mf = 0; mf < 8; ++mf) {
        int gr = m0 + wr * 128 + mf * 16 + crow;
#pragma unroll
        for (int nf = 0; nf < 4; ++nf) {
            int gc = n0 + wc * 64 + nf * 16 + ccol;
            f32x4 v = acc[mf][nf];
#pragma unroll
            for (int r2 = 0; r2 < 4; ++r2) {
                float o = v[r2];
                if (EPI == 1) o = gelu_exact(o + bias[gc]);
                if (OUTF) Cf[(size_t)(gr + r2) * Ncols + gc] = o;
                if (OUTB) Cb[(size_t)(gr + r2) * Ncols + gc] = f2bf(o);
            }
        }
    }
}

// ---------- top-8 + softmax from bf16 sims: one wave per row ----------
#define INS8(v_, i_)                                                     \
    do {                                                                 \
        float cv = (v_); int ci = (i_);                                  \
        _Pragma("unroll")                                                \
        for (int p = 0; p < 8; ++p) {                                    \
            bool sw = cv > val[p];                                       \
            float tv = val[p]; int tix = idx[p];                         \
            val[p] = sw ? cv : val[p];                                   \
            idx[p] = sw ? ci : idx[p];                                   \
            cv = sw ? tv : cv; ci = sw ? tix : ci;                       \
        }                                                                \
    } while (0)

__global__ __launch_bounds__(256) void topk_kernel(
        const unsigned short* __restrict__ sims, const float* __restrict__ qinv,
        float* __restrict__ topw, int* __restrict__ topi) {
    int wid = threadIdx.x >> 6, l = threadIdx.x & 63;
    int row = blockIdx.x * 4 + wid;
    const unsigned short* sr = sims + (size_t)row * SKEYS + l * 32;
    float val[8]; int idx[8];
#pragma unroll
    for (int j = 0; j < 8; ++j) { val[j] = -1e30f; idx[j] = 0; }
#pragma unroll
    for (int c = 0; c < 4; ++c) {
        uint4 raw = *(const uint4*)(sr + c * 8);
        unsigned wsv[4] = {raw.x, raw.y, raw.z, raw.w};
#pragma unroll
        for (int q2 = 0; q2 < 4; ++q2) {
            float lo = __uint_as_float(wsv[q2] << 16);
            float hi = __uint_as_float(wsv[q2] & 0xffff0000u);
            int bi0 = l * 32 + c * 8 + q2 * 2;
            if (lo > val[7]) INS8(lo, bi0);
            if (hi > val[7]) INS8(hi, bi0 + 1);
        }
    }
    float ov[8]; int oi[8];
#pragma unroll
    for (int j = 0; j < 8; ++j) {
        float bv = val[0]; int bl = l;
#pragma unroll
        for (int off = 32; off > 0; off >>= 1) {
            float xv = __shfl_xor(bv, off, 64);
            int   xl = __shfl_xor(bl, off, 64);
            if (xv > bv || (xv == bv && xl < bl)) { bv = xv; bl = xl; }
        }
        int bi = __shfl(idx[0], bl, 64);
        ov[j] = bv; oi[j] = bi;
        if (l == bl) {
#pragma unroll
            for (int p = 0; p < 7; ++p) { val[p] = val[p + 1]; idx[p] = idx[p + 1]; }
            val[7] = -1e30f;
        }
    }
    if (l == 0) {
        float qs = qinv[row];
        float m = ov[0] * qs;
        float e[8], ssum = 0.f;
#pragma unroll
        for (int j = 0; j < 8; ++j) { e[j] = expf(ov[j] * qs - m); ssum += e[j]; }
        float inv = 1.0f / ssum;
#pragma unroll
        for (int j = 0; j < 8; ++j) {
            topw[(size_t)row * KTOP + j] = e[j] * inv;
            topi[(size_t)row * KTOP + j] = oi[j];
        }
    }
}

// ---------- retrieved = sum_k w_k * mv[idx_k] -> bf16 ----------
__global__ __launch_bounds__(256) void retrieve_kernel(
        const float* __restrict__ mv, const float* __restrict__ topw,
        const int* __restrict__ topidx, unsigned short* __restrict__ ret) {
    int row = blockIdx.x, t = threadIdx.x;
    __shared__ float w[KTOP];
    __shared__ int   id[KTOP];
    if (t < KTOP) { w[t] = topw[(size_t)row * KTOP + t]; id[t] = topidx[(size_t)row * KTOP + t]; }
    __syncthreads();
    float4 acc = make_float4(0.f, 0.f, 0.f, 0.f);
#pragma unroll
    for (int k = 0; k < KTOP; ++k) {
        float4 v = ((const float4*)(mv + (size_t)id[k] * DDIM))[t];
        float wk = w[k];
        acc.x += wk * v.x; acc.y += wk * v.y; acc.z += wk * v.z; acc.w += wk * v.w;
    }
    ushort4 o;
    o.x = f2bf(acc.x); o.y = f2bf(acc.y); o.z = f2bf(acc.z); o.w = f2bf(acc.w);
    ((ushort4*)(ret + (size_t)row * DDIM))[t] = o;
}

// ---------- gate + residual: out = x + sigmoid(h.gW2+gb2) * ret2 ----------
__global__ __launch_bounds__(256) void out_kernel(
        const float* __restrict__ x, const unsigned short* __restrict__ hbf,
        const float* __restrict__ gW2, const float* __restrict__ gb2,
        const unsigned short* __restrict__ ret2, float* __restrict__ out) {
    int row = blockIdx.x, t = threadIdx.x;
    const unsigned short* hr = hbf + (size_t)row * HDIM;
    float p = bf2f(hr[t]) * gW2[t] + bf2f(hr[t + 256]) * gW2[t + 256];
    p = wave_sum(p);
    __shared__ float wsum[4];
    if ((t & 63) == 0) wsum[t >> 6] = p;
    __syncthreads();
    float z = wsum[0] + wsum[1] + wsum[2] + wsum[3] + gb2[0];
    float gate = 1.0f / (1.0f + expf(-z));
    float4 xv = ((const float4*)(x + (size_t)row * DDIM))[t];
    uint2 rv = ((const uint2*)(ret2 + (size_t)row * DDIM))[t];
    float r0 = __uint_as_float(rv.x << 16);
    float r1 = __uint_as_float(rv.x & 0xffff0000u);
    float r2 = __uint_as_float(rv.y << 16);
    float r3 = __uint_as_float(rv.y & 0xffff0000u);
    float4 o = make_float4(xv.x + gate * r0, xv.y + gate * r1,
                           xv.z + gate * r2, xv.w + gate * r3);
    ((float4*)(out + (size_t)row * DDIM))[t] = o;
}

extern "C" void kernel_launch(void* const* d_in, const int* in_sizes, int n_in,
                              void* d_out, int out_size, void* d_ws, size_t ws_size,
                              hipStream_t stream) {
    (void)in_sizes; (void)n_in; (void)out_size; (void)ws_size;
    const float* x   = (const float*)d_in[0];
    const float* mk  = (const float*)d_in[1];
    const float* mv  = (const float*)d_in[2];
    const float* Wq  = (const float*)d_in[3];
    const float* Wo  = (const float*)d_in[4];
    const float* gW1 = (const float*)d_in[5];
    const float* gb1 = (const float*)d_in[6];
    const float* gW2 = (const float*)d_in[7];
    const float* gb2 = (const float*)d_in[8];
    float* out = (float*)d_out;

    // workspace (~165 MB), lifetime-aliased
    char* w = (char*)d_ws;
    unsigned short* x_bf   = (unsigned short*)w;  w += (size_t)NROWS * DDIM * 2;
    unsigned short* qret   = (unsigned short*)w;  w += (size_t)NROWS * DDIM * 2;   // q_bf then ret_bf
    unsigned short* kn_bf  = (unsigned short*)w;  w += (size_t)SKEYS * DDIM * 2;
    unsigned short* wq_bf  = (unsigned short*)w;  w += (size_t)DDIM * DDIM * 2;
    unsigned short* wo_bf  = (unsigned short*)w;  w += (size_t)DDIM * DDIM * 2;
    unsigned short* gw1_bf = (unsigned short*)w;  w += (size_t)HDIM * 2 * DDIM * 2;
    unsigned short* sims   = (unsigned short*)w;  w += (size_t)NROWS * SKEYS * 2;  // later ret2_bf
    float* topw  = (float*)w;                     w += (size_t)NROWS * KTOP * 4;
    int*   topi  = (int*)w;                       w += (size_t)NROWS * KTOP * 4;
    float* qinvb = (float*)w;                     w += (size_t)NROWS * 4;
    unsigned short* h_bf = (unsigned short*)w;    w += (size_t)NROWS * HDIM * 2;
    unsigned short* ret2_bf = sims;               // alias: sims dead after topk

    f2bf_kernel<<<2048, 256, 0, stream>>>(x,   x_bf,   NROWS * DDIM / 4);
    f2bf_kernel<<<512,  256, 0, stream>>>(Wq,  wq_bf,  DDIM * DDIM / 4);
    f2bf_kernel<<<512,  256, 0, stream>>>(Wo,  wo_bf,  DDIM * DDIM / 4);
    f2bf_kernel<<<512,  256, 0, stream>>>(gW1, gw1_bf, HDIM * 2 * DDIM / 4);
    knorm_kernel<<<SKEYS, 256, 0, stream>>>(mk, kn_bf);

    // q_bf = x @ Wq^T
    gemm256<0, false, true><<<dim3(DDIM / 256, NROWS / 256), 512, 0, stream>>>(
        x_bf, x_bf, DDIM, DDIM, wq_bf, nullptr, nullptr, qret, DDIM);

    qinv_kernel<<<NROWS / 4, 256, 0, stream>>>(qret, qinvb);

    // sims = q_bf @ kn^T
    gemm256<0, false, true><<<dim3(SKEYS / 256, NROWS / 256), 512, 0, stream>>>(
        qret, qret, DDIM, DDIM, kn_bf, nullptr, nullptr, sims, SKEYS);

    topk_kernel<<<NROWS / 4, 256, 0, stream>>>(sims, qinvb, topw, topi);

    retrieve_kernel<<<NROWS, 256, 0, stream>>>(mv, topw, topi, qret);  // -> ret_bf

    // ret2_bf = ret @ Wo^T (bf16 only; no fp32 round-trip)
    gemm256<0, false, true><<<dim3(DDIM / 256, NROWS / 256), 512, 0, stream>>>(
        qret, qret, DDIM, DDIM, wo_bf, nullptr, nullptr, ret2_bf, DDIM);

    // h_bf = gelu([x | ret2] @ gW1^T + gb1)
    gemm256<1, false, true><<<dim3(HDIM / 256, NROWS / 256), 512, 0, stream>>>(
        x_bf, ret2_bf, DDIM, 2 * DDIM, gw1_bf, gb1, nullptr, h_bf, HDIM);

    out_kernel<<<NROWS, 256, 0, stream>>>(x, h_bf, gW2, gb2, ret2_bf, out);
}

// Round 5
// 404.785 us; speedup vs baseline: 8.6669x; 1.0402x over previous
//
#include <hip/hip_runtime.h>
#include <math.h>

// B=4, T=4096 -> NROWS=16384; D=1024; S=2048; K=8; H=512
#define NROWS 16384
#define DDIM  1024
#define SKEYS 2048
#define KTOP  8
#define HDIM  512
#define PBLK  16   // SKEYS/128 partial col-blocks per row

typedef short  s16x8 __attribute__((ext_vector_type(8)));
typedef float  f32x4 __attribute__((ext_vector_type(4)));

#define GL16(g, l) __builtin_amdgcn_global_load_lds(                      \
    (const __attribute__((address_space(1))) void*)(g),                   \
    (__attribute__((address_space(3))) void*)(l), 16, 0, 0)

__device__ __forceinline__ float wave_sum(float v) {
#pragma unroll
    for (int off = 32; off > 0; off >>= 1) v += __shfl_xor(v, off, 64);
    return v;
}

__device__ __forceinline__ unsigned short f2bf(float f) {
    union { float f; unsigned u; } c; c.f = f;
    unsigned u = c.u;
    unsigned r = (u + 0x7FFFu + ((u >> 16) & 1u)) >> 16;
    return (unsigned short)r;
}
__device__ __forceinline__ float bf2f(unsigned short h) {
    union { unsigned u; float f; } c; c.u = ((unsigned)h) << 16;
    return c.f;
}

__device__ __forceinline__ float gelu_exact(float v) {
    return 0.5f * v * (1.0f + erff(v * 0.7071067811865475f));
}

// ---------- fp32 -> bf16 convert ----------
__global__ __launch_bounds__(256) void f2bf_kernel(const float* __restrict__ in,
                                                   unsigned short* __restrict__ out, int n4) {
    for (int i = blockIdx.x * 256 + threadIdx.x; i < n4; i += gridDim.x * 256) {
        float4 v = ((const float4*)in)[i];
        ushort4 o;
        o.x = f2bf(v.x); o.y = f2bf(v.y); o.z = f2bf(v.z); o.w = f2bf(v.w);
        ((ushort4*)out)[i] = o;
    }
}

// ---------- normalize memory_keys -> bf16 ----------
__global__ __launch_bounds__(256) void knorm_kernel(const float* __restrict__ mk,
                                                    unsigned short* __restrict__ kn) {
    int s = blockIdx.x, t = threadIdx.x;
    float4 v = ((const float4*)(mk + (size_t)s * DDIM))[t];
    float ss = v.x * v.x + v.y * v.y + v.z * v.z + v.w * v.w;
    ss = wave_sum(ss);
    __shared__ float wsum[4];
    if ((t & 63) == 0) wsum[t >> 6] = ss;
    __syncthreads();
    float tot = wsum[0] + wsum[1] + wsum[2] + wsum[3];
    float sc = 1.0f / fmaxf(sqrtf(tot), 1e-12f);
    ushort4 o;
    o.x = f2bf(v.x * sc); o.y = f2bf(v.y * sc); o.z = f2bf(v.z * sc); o.w = f2bf(v.w * sc);
    ((ushort4*)(kn + (size_t)s * DDIM))[t] = o;
}

// ---------- qinv from bf16 q ----------
__global__ __launch_bounds__(256) void qinv_kernel(const unsigned short* __restrict__ qbf,
                                                   float* __restrict__ qinv) {
    int wid = threadIdx.x >> 6, l = threadIdx.x & 63;
    int row = blockIdx.x * 4 + wid;
    const unsigned short* p = qbf + (size_t)row * DDIM + l * 16;
    uint4 a = *(const uint4*)p;
    uint4 b = *(const uint4*)(p + 8);
    float ss = 0.f;
    unsigned wsv[8] = {a.x, a.y, a.z, a.w, b.x, b.y, b.z, b.w};
#pragma unroll
    for (int j = 0; j < 8; ++j) {
        float lo = __uint_as_float(wsv[j] << 16);
        float hi = __uint_as_float(wsv[j] & 0xffff0000u);
        ss += lo * lo + hi * hi;
    }
    ss = wave_sum(ss);
    if (l == 0) qinv[row] = 1.0f / fmaxf(sqrtf(ss), 1e-12f);
}

#define INS8(v_, i_)                                                     \
    do {                                                                 \
        float insv_ = (v_); int insi_ = (i_);                            \
        _Pragma("unroll")                                                \
        for (int p_ = 0; p_ < 8; ++p_) {                                 \
            bool sw_ = insv_ > val[p_];                                  \
            float tv_ = val[p_]; int tix_ = idx[p_];                     \
            val[p_] = sw_ ? insv_ : val[p_];                             \
            idx[p_] = sw_ ? insi_ : idx[p_];                             \
            insv_ = sw_ ? tv_ : insv_; insi_ = sw_ ? tix_ : insi_;       \
        }                                                                \
    } while (0)

// ---------- 128x128 bf16 MFMA GEMM, BK=64, 4 waves, dbuf + counted vmcnt ----------
// MODE 0: C -> bf16.  MODE 1: gelu(C+bias) -> bf16.  MODE 2: per-row partial
// top-8 of the fp32 accumulator tile -> pval/pidx (no C write).
// LDS [128][64] bf16 rows (128B), swizzle chunk' = chunk ^ (row&7), applied
// inverse on the gload_lds global source (dest linear) and on ds_read.
template<int MODE>
__global__ __launch_bounds__(256, 2) void gemm128(
        const unsigned short* __restrict__ A0, const unsigned short* __restrict__ A1,
        int K0, int Ktot,
        const unsigned short* __restrict__ Bm, const float* __restrict__ bias,
        unsigned short* __restrict__ Cb, int Ncols,
        float* __restrict__ pval, int* __restrict__ pidx) {
    __shared__ __align__(16) char lds_raw[66048];  // 64KB tiles / 128x129 f32 scan
    unsigned short* Asp = (unsigned short*)lds_raw;           // [2][8192]
    unsigned short* Bsp = (unsigned short*)(lds_raw + 32768); // [2][8192]

    int tid = threadIdx.x, l = tid & 63, wid = tid >> 6;
    // XCD-chunked block swizzle (all grids divisible by 8)
    int gx = gridDim.x;
    int nwg = gx * gridDim.y;
    int bid = blockIdx.y * gx + blockIdx.x;
    int cpx = nwg >> 3;
    int sbid = (bid & 7) * cpx + (bid >> 3);
    int m0 = (sbid / gx) * 128;
    int n0 = (sbid % gx) * 128;

    int wr = wid >> 1, wc = wid & 1;       // 2x2 waves; per-wave C = 64x64
    int K1 = Ktot - K0;
    int NT = Ktot >> 6;

    f32x4 acc[4][4];
#pragma unroll
    for (int i = 0; i < 4; ++i)
#pragma unroll
        for (int j = 0; j < 4; ++j) acc[i][j] = (f32x4){0.f, 0.f, 0.f, 0.f};

    // staging: issue i covers tile rows [i*32, i*32+32); HW puts lane at
    // row = i*32 + (t>>3), chunk = t&7; source chunk inverse-swizzled.
    int srow   = tid >> 3;                 // 0..31
    int schunk = (tid & 7) ^ (srow & 7);
    int offA0[4], offA1[4], offB[4];
#pragma unroll
    for (int i = 0; i < 4; ++i) {
        int ra = m0 + i * 32 + srow;
        offA0[i] = ra * K0;
        offA1[i] = ra * K1;
        offB[i]  = (n0 + i * 32 + srow) * Ktot;
    }
    int ldsU = wid * 512;                  // ushort offset of this wave within an issue

#define STAGE(bsel, kt_)                                                       \
    do {                                                                       \
        int gk_ = (kt_) * 64 + schunk * 8;                                     \
        _Pragma("unroll")                                                      \
        for (int i_ = 0; i_ < 4; ++i_) {                                       \
            const unsigned short* ga_ = (gk_ < K0)                             \
                ? A0 + offA0[i_] + gk_                                         \
                : A1 + offA1[i_] + (gk_ - K0);                                 \
            GL16(ga_, &Asp[(bsel) * 8192 + i_ * 2048 + ldsU]);                 \
            GL16(Bm + offB[i_] + gk_, &Bsp[(bsel) * 8192 + i_ * 2048 + ldsU]); \
        }                                                                      \
    } while (0)

    STAGE(0, 0);

    for (int kt = 0; kt < NT; ++kt) {
        int b = kt & 1;
        if (kt + 1 < NT) {
            STAGE(b ^ 1, kt + 1);                              // 16 outstanding
            asm volatile("s_waitcnt vmcnt(8)" ::: "memory");   // this tile's 8 done
        } else {
            asm volatile("s_waitcnt vmcnt(0)" ::: "memory");
        }
        __builtin_amdgcn_s_barrier();
        asm volatile("" ::: "memory");

        s16x8 af[2][4], bfr[2][4];
#pragma unroll
        for (int ks = 0; ks < 2; ++ks) {
            int ch = ((ks << 2) + (l >> 4)) ^ (l & 7);
#pragma unroll
            for (int mf = 0; mf < 4; ++mf) {
                int row = wr * 64 + mf * 16 + (l & 15);
                af[ks][mf] = *(const s16x8*)&Asp[b * 8192 + row * 64 + ch * 8];
            }
#pragma unroll
            for (int nf = 0; nf < 4; ++nf) {
                int row = wc * 64 + nf * 16 + (l & 15);
                bfr[ks][nf] = *(const s16x8*)&Bsp[b * 8192 + row * 64 + ch * 8];
            }
        }
        __builtin_amdgcn_s_setprio(1);
#pragma unroll
        for (int ks = 0; ks < 2; ++ks)
#pragma unroll
            for (int mf = 0; mf < 4; ++mf)
#pragma unroll
                for (int nf = 0; nf < 4; ++nf)
                    acc[mf][nf] = __builtin_amdgcn_mfma_f32_16x16x32_bf16(
                        af[ks][mf], bfr[ks][nf], acc[mf][nf], 0, 0, 0);
        __builtin_amdgcn_s_setprio(0);
        asm volatile("" ::: "memory");
        __builtin_amdgcn_s_barrier();      // readers done -> next STAGE may overwrite
        asm volatile("" ::: "memory");
    }
#undef STAGE

    int crow = (l >> 4) << 2;
    int ccol = l & 15;

    if (MODE != 2) {
#pragma unroll
        for (int mf = 0; mf < 4; ++mf) {
            int gr = m0 + wr * 64 + mf * 16 + crow;
#pragma unroll
            for (int nf = 0; nf < 4; ++nf) {
                int gc = n0 + wc * 64 + nf * 16 + ccol;
                f32x4 v = acc[mf][nf];
#pragma unroll
                for (int r2 = 0; r2 < 4; ++r2) {
                    float o = v[r2];
                    if (MODE == 1) o = gelu_exact(o + bias[gc]);
                    Cb[(size_t)(gr + r2) * Ncols + gc] = f2bf(o);
                }
            }
        }
    } else {
        // ---- fused per-row partial top-8 over this 128-col block ----
        float* ct = (float*)lds_raw;       // [128][129] f32
#pragma unroll
        for (int mf = 0; mf < 4; ++mf)
#pragma unroll
            for (int nf = 0; nf < 4; ++nf) {
                f32x4 v = acc[mf][nf];
#pragma unroll
                for (int r2 = 0; r2 < 4; ++r2)
                    ct[(wr * 64 + mf * 16 + crow + r2) * 129 +
                       (wc * 64 + nf * 16 + ccol)] = v[r2];
            }
        __syncthreads();
        int r = tid >> 1, h = tid & 1;     // 2 threads per row, 64 cols each
        float val[8]; int idx[8];
#pragma unroll
        for (int j = 0; j < 8; ++j) { val[j] = -1e30f; idx[j] = 0; }
        for (int j = 0; j < 64; ++j) {
            int c = h * 64 + ((j + (h << 4)) & 63);   // stagger halves (banks)
            float v = ct[r * 129 + c];
            if (v > val[7]) INS8(v, n0 + c);
        }
        __syncthreads();
        float* mcv = ct;                   // [256][8] f32
        int*   mci = (int*)(ct + 2048);    // [256][8] i32
#pragma unroll
        for (int k = 0; k < 8; ++k) { mcv[tid * 8 + k] = val[k]; mci[tid * 8 + k] = idx[k]; }
        __syncthreads();
        if (h == 0) {
#pragma unroll
            for (int k = 0; k < 8; ++k) {
                float mv_ = mcv[(tid + 1) * 8 + k];
                int   mi_ = mci[(tid + 1) * 8 + k];
                if (mv_ > val[7]) INS8(mv_, mi_);
            }
            int rg = m0 + r, bn = n0 >> 7;
#pragma unroll
            for (int k = 0; k < 8; ++k) {
                pval[(size_t)rg * (PBLK * 8) + bn * 8 + k] = val[k];
                pidx[(size_t)rg * (PBLK * 8) + bn * 8 + k] = idx[k];
            }
        }
    }
}

// ---------- merge 16x8 partials -> top-8 + softmax; one wave per row ----------
__global__ __launch_bounds__(256) void topk_merge(
        const float* __restrict__ pval, const int* __restrict__ pidx,
        const float* __restrict__ qinv,
        float* __restrict__ topw, int* __restrict__ topi) {
    int wid = threadIdx.x >> 6, l = threadIdx.x & 63;
    int row = blockIdx.x * 4 + wid;
    const float* pv = pval + (size_t)row * (PBLK * 8);
    const int*   pi = pidx + (size_t)row * (PBLK * 8);
    float val[8]; int idx[8];
#pragma unroll
    for (int j = 0; j < 8; ++j) { val[j] = -1e30f; idx[j] = 0; }
    float v0 = pv[l];      int i0 = pi[l];
    float v1 = pv[l + 64]; int i1 = pi[l + 64];
    if (v0 > val[7]) INS8(v0, i0);
    if (v1 > val[7]) INS8(v1, i1);
    float ov[8]; int oi[8];
#pragma unroll
    for (int j = 0; j < 8; ++j) {
        float bv = val[0]; int bl = l;
#pragma unroll
        for (int off = 32; off > 0; off >>= 1) {
            float xv = __shfl_xor(bv, off, 64);
            int   xl = __shfl_xor(bl, off, 64);
            if (xv > bv || (xv == bv && xl < bl)) { bv = xv; bl = xl; }
        }
        int bi = __shfl(idx[0], bl, 64);
        ov[j] = bv; oi[j] = bi;
        if (l == bl) {
#pragma unroll
            for (int p = 0; p < 7; ++p) { val[p] = val[p + 1]; idx[p] = idx[p + 1]; }
            val[7] = -1e30f;
        }
    }
    if (l == 0) {
        float qs = qinv[row];
        float m = ov[0] * qs;
        float e[8], ssum = 0.f;
#pragma unroll
        for (int j = 0; j < 8; ++j) { e[j] = expf(ov[j] * qs - m); ssum += e[j]; }
        float inv = 1.0f / ssum;
#pragma unroll
        for (int j = 0; j < 8; ++j) {
            topw[(size_t)row * KTOP + j] = e[j] * inv;
            topi[(size_t)row * KTOP + j] = oi[j];
        }
    }
}

// ---------- retrieved = sum_k w_k * mv[idx_k] -> bf16; one wave per row ----------
__global__ __launch_bounds__(256) void retrieve_kernel(
        const float* __restrict__ mv, const float* __restrict__ topw,
        const int* __restrict__ topidx, unsigned short* __restrict__ ret) {
    int wid = threadIdx.x >> 6, l = threadIdx.x & 63;
    int row = blockIdx.x * 4 + wid;
    float w[KTOP]; int id[KTOP];
#pragma unroll
    for (int k = 0; k < KTOP; ++k) {
        w[k]  = topw[(size_t)row * KTOP + k];
        id[k] = topidx[(size_t)row * KTOP + k];
    }
    float4 a[4];
#pragma unroll
    for (int j = 0; j < 4; ++j) a[j] = make_float4(0.f, 0.f, 0.f, 0.f);
#pragma unroll
    for (int k = 0; k < KTOP; ++k) {
        const float4* vr = (const float4*)(mv + (size_t)id[k] * DDIM + l * 16);
        float wk = w[k];
#pragma unroll
        for (int j = 0; j < 4; ++j) {
            float4 v = vr[j];
            a[j].x += wk * v.x; a[j].y += wk * v.y;
            a[j].z += wk * v.z; a[j].w += wk * v.w;
        }
    }
    ushort4* po = (ushort4*)(ret + (size_t)row * DDIM + l * 16);
#pragma unroll
    for (int j = 0; j < 4; ++j) {
        ushort4 o;
        o.x = f2bf(a[j].x); o.y = f2bf(a[j].y); o.z = f2bf(a[j].z); o.w = f2bf(a[j].w);
        po[j] = o;
    }
}

// ---------- gate + residual; one wave per row ----------
__global__ __launch_bounds__(256) void out_kernel(
        const unsigned short* __restrict__ x_bf, const unsigned short* __restrict__ hbf,
        const float* __restrict__ gW2, const float* __restrict__ gb2,
        const unsigned short* __restrict__ ret2, float* __restrict__ out) {
    int wid = threadIdx.x >> 6, l = threadIdx.x & 63;
    int row = blockIdx.x * 4 + wid;
    uint4 hv = *(const uint4*)(hbf + (size_t)row * HDIM + l * 8);
    float4 wa = *(const float4*)(gW2 + l * 8);
    float4 wb = *(const float4*)(gW2 + l * 8 + 4);
    unsigned hw[4] = {hv.x, hv.y, hv.z, hv.w};
    float wf[8] = {wa.x, wa.y, wa.z, wa.w, wb.x, wb.y, wb.z, wb.w};
    float p = 0.f;
#pragma unroll
    for (int j = 0; j < 4; ++j) {
        p += __uint_as_float(hw[j] << 16) * wf[2 * j];
        p += __uint_as_float(hw[j] & 0xffff0000u) * wf[2 * j + 1];
    }
    p = wave_sum(p);
    float gate = 1.0f / (1.0f + expf(-(p + gb2[0])));
#pragma unroll
    for (int part = 0; part < 2; ++part) {
        size_t base = (size_t)row * DDIM + part * 512 + l * 8;
        uint4 xv = *(const uint4*)(x_bf + base);
        uint4 rv = *(const uint4*)(ret2 + base);
        unsigned xw[4] = {xv.x, xv.y, xv.z, xv.w};
        unsigned rw[4] = {rv.x, rv.y, rv.z, rv.w};
        float o[8];
#pragma unroll
        for (int j = 0; j < 4; ++j) {
            o[2 * j]     = __uint_as_float(xw[j] << 16)
                         + gate * __uint_as_float(rw[j] << 16);
            o[2 * j + 1] = __uint_as_float(xw[j] & 0xffff0000u)
                         + gate * __uint_as_float(rw[j] & 0xffff0000u);
        }
        float4* po = (float4*)(out + base);
        po[0] = make_float4(o[0], o[1], o[2], o[3]);
        po[1] = make_float4(o[4], o[5], o[6], o[7]);
    }
}

extern "C" void kernel_launch(void* const* d_in, const int* in_sizes, int n_in,
                              void* d_out, int out_size, void* d_ws, size_t ws_size,
                              hipStream_t stream) {
    (void)in_sizes; (void)n_in; (void)out_size; (void)ws_size;
    const float* x   = (const float*)d_in[0];
    const float* mk  = (const float*)d_in[1];
    const float* mv  = (const float*)d_in[2];
    const float* Wq  = (const float*)d_in[3];
    const float* Wo  = (const float*)d_in[4];
    const float* gW1 = (const float*)d_in[5];
    const float* gb1 = (const float*)d_in[6];
    const float* gW2 = (const float*)d_in[7];
    const float* gb2 = (const float*)d_in[8];
    float* out = (float*)d_out;

    // workspace (~145 MB), lifetime-aliased
    char* w = (char*)d_ws;
    unsigned short* x_bf    = (unsigned short*)w;  w += (size_t)NROWS * DDIM * 2;
    unsigned short* qret    = (unsigned short*)w;  w += (size_t)NROWS * DDIM * 2;  // q then ret
    unsigned short* kn_bf   = (unsigned short*)w;  w += (size_t)SKEYS * DDIM * 2;
    unsigned short* wq_bf   = (unsigned short*)w;  w += (size_t)DDIM * DDIM * 2;
    unsigned short* wo_bf   = (unsigned short*)w;  w += (size_t)DDIM * DDIM * 2;
    unsigned short* gw1_bf  = (unsigned short*)w;  w += (size_t)HDIM * 2 * DDIM * 2;
    unsigned short* ret2_bf = (unsigned short*)w;  w += (size_t)NROWS * DDIM * 2;
    unsigned short* h_bf    = (unsigned short*)w;  w += (size_t)NROWS * HDIM * 2;
    float* pval  = (float*)w;                      w += (size_t)NROWS * PBLK * 8 * 4;
    int*   pidx  = (int*)w;                        w += (size_t)NROWS * PBLK * 8 * 4;
    float* topw  = (float*)w;                      w += (size_t)NROWS * KTOP * 4;
    int*   topi  = (int*)w;                        w += (size_t)NROWS * KTOP * 4;
    float* qinvb = (float*)w;                      w += (size_t)NROWS * 4;

    f2bf_kernel<<<2048, 256, 0, stream>>>(x,   x_bf,   NROWS * DDIM / 4);
    f2bf_kernel<<<512,  256, 0, stream>>>(Wq,  wq_bf,  DDIM * DDIM / 4);
    f2bf_kernel<<<512,  256, 0, stream>>>(Wo,  wo_bf,  DDIM * DDIM / 4);
    f2bf_kernel<<<512,  256, 0, stream>>>(gW1, gw1_bf, HDIM * 2 * DDIM / 4);
    knorm_kernel<<<SKEYS, 256, 0, stream>>>(mk, kn_bf);

    // q = x @ Wq^T -> bf16
    gemm128<0><<<dim3(DDIM / 128, NROWS / 128), 256, 0, stream>>>(
        x_bf, x_bf, DDIM, DDIM, wq_bf, nullptr, qret, DDIM, nullptr, nullptr);

    qinv_kernel<<<NROWS / 4, 256, 0, stream>>>(qret, qinvb);

    // sims partial top-8 (fused epilogue; no sims matrix materialized)
    gemm128<2><<<dim3(SKEYS / 128, NROWS / 128), 256, 0, stream>>>(
        qret, qret, DDIM, DDIM, kn_bf, nullptr, nullptr, SKEYS, pval, pidx);

    topk_merge<<<NROWS / 4, 256, 0, stream>>>(pval, pidx, qinvb, topw, topi);

    retrieve_kernel<<<NROWS / 4, 256, 0, stream>>>(mv, topw, topi, qret);  // -> ret_bf

    // ret2 = ret @ Wo^T -> bf16
    gemm128<0><<<dim3(DDIM / 128, NROWS / 128), 256, 0, stream>>>(
        qret, qret, DDIM, DDIM, wo_bf, nullptr, ret2_bf, DDIM, nullptr, nullptr);

    // h = gelu([x | ret2] @ gW1^T + gb1) -> bf16
    gemm128<1><<<dim3(HDIM / 128, NROWS / 128), 256, 0, stream>>>(
        x_bf, ret2_bf, DDIM, 2 * DDIM, gw1_bf, gb1, h_bf, HDIM, nullptr, nullptr);

    out_kernel<<<NROWS / 4, 256, 0, stream>>>(x_bf, h_bf, gW2, gb2, ret2_bf, out);
}

// Round 7
// 386.470 us; speedup vs baseline: 9.0776x; 1.0474x over previous
//
#include <hip/hip_runtime.h>
#include <math.h>

// B=4, T=4096 -> NROWS=16384; D=1024; S=2048; K=8; H=512
#define NROWS 16384
#define DDIM  1024
#define SKEYS 2048
#define KTOP  8
#define HDIM  512

typedef short  s16x8 __attribute__((ext_vector_type(8)));
typedef float  f32x4 __attribute__((ext_vector_type(4)));

#define GL16(g, l) __builtin_amdgcn_global_load_lds(                      \
    (const __attribute__((address_space(1))) void*)(g),                   \
    (__attribute__((address_space(3))) void*)(l), 16, 0, 0)

__device__ __forceinline__ float wave_sum(float v) {
#pragma unroll
    for (int off = 32; off > 0; off >>= 1) v += __shfl_xor(v, off, 64);
    return v;
}

__device__ __forceinline__ unsigned short f2bf(float f) {
    union { float f; unsigned u; } c; c.f = f;
    unsigned u = c.u;
    unsigned r = (u + 0x7FFFu + ((u >> 16) & 1u)) >> 16;
    return (unsigned short)r;
}
__device__ __forceinline__ float bf2f(unsigned short h) {
    union { unsigned u; float f; } c; c.u = ((unsigned)h) << 16;
    return c.f;
}

__device__ __forceinline__ float gelu_exact(float v) {
    return 0.5f * v * (1.0f + erff(v * 0.7071067811865475f));
}

// ---------- fp32 -> bf16 convert ----------
__global__ __launch_bounds__(256) void f2bf_kernel(const float* __restrict__ in,
                                                   unsigned short* __restrict__ out, int n4) {
    for (int i = blockIdx.x * 256 + threadIdx.x; i < n4; i += gridDim.x * 256) {
        float4 v = ((const float4*)in)[i];
        ushort4 o;
        o.x = f2bf(v.x); o.y = f2bf(v.y); o.z = f2bf(v.z); o.w = f2bf(v.w);
        ((ushort4*)out)[i] = o;
    }
}

// ---------- normalize memory_keys -> bf16 ----------
__global__ __launch_bounds__(256) void knorm_kernel(const float* __restrict__ mk,
                                                    unsigned short* __restrict__ kn) {
    int s = blockIdx.x, t = threadIdx.x;
    float4 v = ((const float4*)(mk + (size_t)s * DDIM))[t];
    float ss = v.x * v.x + v.y * v.y + v.z * v.z + v.w * v.w;
    ss = wave_sum(ss);
    __shared__ float wsum[4];
    if ((t & 63) == 0) wsum[t >> 6] = ss;
    __syncthreads();
    float tot = wsum[0] + wsum[1] + wsum[2] + wsum[3];
    float sc = 1.0f / fmaxf(sqrtf(tot), 1e-12f);
    ushort4 o;
    o.x = f2bf(v.x * sc); o.y = f2bf(v.y * sc); o.z = f2bf(v.z * sc); o.w = f2bf(v.w * sc);
    ((ushort4*)(kn + (size_t)s * DDIM))[t] = o;
}

// ---------- qinv from bf16 q ----------
__global__ __launch_bounds__(256) void qinv_kernel(const unsigned short* __restrict__ qbf,
                                                   float* __restrict__ qinv) {
    int wid = threadIdx.x >> 6, l = threadIdx.x & 63;
    int row = blockIdx.x * 4 + wid;
    const unsigned short* p = qbf + (size_t)row * DDIM + l * 16;
    uint4 a = *(const uint4*)p;
    uint4 b = *(const uint4*)(p + 8);
    float ss = 0.f;
    unsigned wsv[8] = {a.x, a.y, a.z, a.w, b.x, b.y, b.z, b.w};
#pragma unroll
    for (int j = 0; j < 8; ++j) {
        float lo = __uint_as_float(wsv[j] << 16);
        float hi = __uint_as_float(wsv[j] & 0xffff0000u);
        ss += lo * lo + hi * hi;
    }
    ss = wave_sum(ss);
    if (l == 0) qinv[row] = 1.0f / fmaxf(sqrtf(ss), 1e-12f);
}

#define INS8(v_, i_)                                                     \
    do {                                                                 \
        float insv_ = (v_); int insi_ = (i_);                            \
        _Pragma("unroll")                                                \
        for (int p_ = 0; p_ < 8; ++p_) {                                 \
            bool sw_ = insv_ > val[p_];                                  \
            float tv_ = val[p_]; int tix_ = idx[p_];                     \
            val[p_] = sw_ ? insv_ : val[p_];                             \
            idx[p_] = sw_ ? insi_ : idx[p_];                             \
            insv_ = sw_ ? tv_ : insv_; insi_ = sw_ ? tix_ : insi_;       \
        }                                                                \
    } while (0)

// ---------- 128x128 bf16 MFMA GEMM, BK=32, 4 waves, 32KB dbuf LDS ----------
// m97-faithful: 2 barriers per K-tile, counted vmcnt(4), 3 blocks/CU.
// MODE 0: C -> bf16.  MODE 1: gelu(C+bias) -> bf16.
// LDS row = 64B (4 x 16B chunks); swizzle: physical chunk = c ^ ((row>>1)&3),
// applied inverse on the gload_lds global source (dest linear) and on ds_read.
template<int MODE, int K0, int KTOT>
__global__ __launch_bounds__(256, 3) void gemm128(
        const unsigned short* __restrict__ A0, const unsigned short* __restrict__ A1,
        const unsigned short* __restrict__ Bm, const float* __restrict__ bias,
        unsigned short* __restrict__ Cb, int Ncols) {
    __shared__ __align__(16) unsigned short As[2][4096];  // [buf][128*32]
    __shared__ __align__(16) unsigned short Bs[2][4096];

    int tid = threadIdx.x, l = tid & 63, wid = tid >> 6;
    // XCD-chunked block swizzle (all grids divisible by 8)
    int gx = gridDim.x;
    int nwg = gx * gridDim.y;
    int bid = blockIdx.y * gx + blockIdx.x;
    int cpx = nwg >> 3;
    int sbid = (bid & 7) * cpx + (bid >> 3);
    int m0 = (sbid / gx) * 128;
    int n0 = (sbid % gx) * 128;

    int wr = wid >> 1, wc = wid & 1;       // 2x2 waves; per-wave C = 64x64
    constexpr int K1 = KTOT - K0;
    constexpr int NT = KTOT >> 5;          // K-tiles of 32

    f32x4 acc[4][4];
#pragma unroll
    for (int i = 0; i < 4; ++i)
#pragma unroll
        for (int j = 0; j < 4; ++j) acc[i][j] = (f32x4){0.f, 0.f, 0.f, 0.f};

    // staging: issue i covers tile rows [i*64, i*64+64); thread -> row=t>>2,
    // 16B chunk = t&3, source chunk inverse-swizzled by (row>>1)&3.
    // HW writes wave-uniform base + lane*16B = 1024B/wave = 16 rows.
    int srow   = tid >> 2;                 // 0..63
    int schunk = (tid & 3) ^ ((srow >> 1) & 3);
    int offA0[2], offA1[2], offB[2];
#pragma unroll
    for (int i = 0; i < 2; ++i) {
        int ra = m0 + i * 64 + srow;
        offA0[i] = ra * K0;
        offA1[i] = ra * K1;
        offB[i]  = (n0 + i * 64 + srow) * KTOT;
    }
    int ldsU = wid * 512;                  // ushorts: 1024B per wave (16 rows x 64B)

#define STAGE(bsel, kt_)                                                       \
    do {                                                                       \
        int gk_ = (kt_) * 32 + schunk * 8;                                     \
        _Pragma("unroll")                                                      \
        for (int i_ = 0; i_ < 2; ++i_) {                                       \
            const unsigned short* ga_ = (K0 == KTOT || gk_ < K0)               \
                ? A0 + offA0[i_] + gk_                                         \
                : A1 + offA1[i_] + (gk_ - K0);                                 \
            GL16(ga_, &As[bsel][i_ * 2048 + ldsU]);                            \
            GL16(Bm + offB[i_] + gk_, &Bs[bsel][i_ * 2048 + ldsU]);            \
        }                                                                      \
    } while (0)

    STAGE(0, 0);   // prologue: 4 loads in flight

    // fragment read geometry (hoisted): ushort index = row*32 + p*8
    int frow = l & 15;
    int fp   = (l >> 4) ^ ((frow >> 1) & 3);     // swizzled physical chunk
    int aoff = (wr * 64 + frow) * 32 + fp * 8;
    int boff = (wc * 64 + frow) * 32 + fp * 8;

#pragma unroll 2
    for (int kt = 0; kt < NT; ++kt) {
        int b = kt & 1;
        if (kt + 1 < NT) {
            STAGE(b ^ 1, kt + 1);                              // 8 outstanding
            asm volatile("s_waitcnt vmcnt(4)" ::: "memory");   // this tile's 4 done
        } else {
            asm volatile("s_waitcnt vmcnt(0)" ::: "memory");
        }
        __builtin_amdgcn_s_barrier();
        asm volatile("" ::: "memory");

        s16x8 af[4], bfr[4];
#pragma unroll
        for (int mf = 0; mf < 4; ++mf)
            af[mf] = *(const s16x8*)&As[b][aoff + mf * 512];
#pragma unroll
        for (int nf = 0; nf < 4; ++nf)
            bfr[nf] = *(const s16x8*)&Bs[b][boff + nf * 512];

        __builtin_amdgcn_s_setprio(1);
#pragma unroll
        for (int mf = 0; mf < 4; ++mf)
#pragma unroll
            for (int nf = 0; nf < 4; ++nf)
                acc[mf][nf] = __builtin_amdgcn_mfma_f32_16x16x32_bf16(
                    af[mf], bfr[nf], acc[mf][nf], 0, 0, 0);
        __builtin_amdgcn_s_setprio(0);
        asm volatile("" ::: "memory");
        __builtin_amdgcn_s_barrier();      // readers done -> next STAGE may overwrite
        asm volatile("" ::: "memory");
    }
#undef STAGE

    int crow = (l >> 4) << 2;
    int ccol = l & 15;
#pragma unroll
    for (int mf = 0; mf < 4; ++mf) {
        int gr = m0 + wr * 64 + mf * 16 + crow;
#pragma unroll
        for (int nf = 0; nf < 4; ++nf) {
            int gc = n0 + wc * 64 + nf * 16 + ccol;
            f32x4 v = acc[mf][nf];
#pragma unroll
            for (int r2 = 0; r2 < 4; ++r2) {
                float o = v[r2];
                if (MODE == 1) o = gelu_exact(o + bias[gc]);
                Cb[(size_t)(gr + r2) * Ncols + gc] = f2bf(o);
            }
        }
    }
}

// ---------- top-8 + softmax from bf16 sims: one wave per row ----------
__global__ __launch_bounds__(256) void topk_kernel(
        const unsigned short* __restrict__ sims, const float* __restrict__ qinv,
        float* __restrict__ topw, int* __restrict__ topi) {
    int wid = threadIdx.x >> 6, l = threadIdx.x & 63;
    int row = blockIdx.x * 4 + wid;
    const unsigned short* sr = sims + (size_t)row * SKEYS + l * 32;
    float val[8]; int idx[8];
#pragma unroll
    for (int j = 0; j < 8; ++j) { val[j] = -1e30f; idx[j] = 0; }
#pragma unroll
    for (int c = 0; c < 4; ++c) {
        uint4 raw = *(const uint4*)(sr + c * 8);
        unsigned wsv[4] = {raw.x, raw.y, raw.z, raw.w};
#pragma unroll
        for (int q2 = 0; q2 < 4; ++q2) {
            float lo = __uint_as_float(wsv[q2] << 16);
            float hi = __uint_as_float(wsv[q2] & 0xffff0000u);
            int bi0 = l * 32 + c * 8 + q2 * 2;
            if (lo > val[7]) INS8(lo, bi0);
            if (hi > val[7]) INS8(hi, bi0 + 1);
        }
    }
    float ov[8]; int oi[8];
#pragma unroll
    for (int j = 0; j < 8; ++j) {
        float bv = val[0]; int bl = l;
#pragma unroll
        for (int off = 32; off > 0; off >>= 1) {
            float xv = __shfl_xor(bv, off, 64);
            int   xl = __shfl_xor(bl, off, 64);
            if (xv > bv || (xv == bv && xl < bl)) { bv = xv; bl = xl; }
        }
        int bi = __shfl(idx[0], bl, 64);
        ov[j] = bv; oi[j] = bi;
        if (l == bl) {
#pragma unroll
            for (int p = 0; p < 7; ++p) { val[p] = val[p + 1]; idx[p] = idx[p + 1]; }
            val[7] = -1e30f;
        }
    }
    if (l == 0) {
        float qs = qinv[row];
        float m = ov[0] * qs;
        float e[8], ssum = 0.f;
#pragma unroll
        for (int j = 0; j < 8; ++j) { e[j] = expf(ov[j] * qs - m); ssum += e[j]; }
        float inv = 1.0f / ssum;
#pragma unroll
        for (int j = 0; j < 8; ++j) {
            topw[(size_t)row * KTOP + j] = e[j] * inv;
            topi[(size_t)row * KTOP + j] = oi[j];
        }
    }
}

// ---------- retrieved = sum_k w_k * mv[idx_k] -> bf16; one wave per row ----------
__global__ __launch_bounds__(256) void retrieve_kernel(
        const float* __restrict__ mv, const float* __restrict__ topw,
        const int* __restrict__ topidx, unsigned short* __restrict__ ret) {
    int wid = threadIdx.x >> 6, l = threadIdx.x & 63;
    int row = blockIdx.x * 4 + wid;
    float w[KTOP]; int id[KTOP];
#pragma unroll
    for (int k = 0; k < KTOP; ++k) {
        w[k]  = topw[(size_t)row * KTOP + k];
        id[k] = topidx[(size_t)row * KTOP + k];
    }
    float4 a[4];
#pragma unroll
    for (int j = 0; j < 4; ++j) a[j] = make_float4(0.f, 0.f, 0.f, 0.f);
#pragma unroll
    for (int k = 0; k < KTOP; ++k) {
        const float4* vr = (const float4*)(mv + (size_t)id[k] * DDIM + l * 16);
        float wk = w[k];
#pragma unroll
        for (int j = 0; j < 4; ++j) {
            float4 v = vr[j];
            a[j].x += wk * v.x; a[j].y += wk * v.y;
            a[j].z += wk * v.z; a[j].w += wk * v.w;
        }
    }
    ushort4* po = (ushort4*)(ret + (size_t)row * DDIM + l * 16);
#pragma unroll
    for (int j = 0; j < 4; ++j) {
        ushort4 o;
        o.x = f2bf(a[j].x); o.y = f2bf(a[j].y); o.z = f2bf(a[j].z); o.w = f2bf(a[j].w);
        po[j] = o;
    }
}

// ---------- gate + residual; one wave per row ----------
__global__ __launch_bounds__(256) void out_kernel(
        const unsigned short* __restrict__ x_bf, const unsigned short* __restrict__ hbf,
        const float* __restrict__ gW2, const float* __restrict__ gb2,
        const unsigned short* __restrict__ ret2, float* __restrict__ out) {
    int wid = threadIdx.x >> 6, l = threadIdx.x & 63;
    int row = blockIdx.x * 4 + wid;
    uint4 hv = *(const uint4*)(hbf + (size_t)row * HDIM + l * 8);
    float4 wa = *(const float4*)(gW2 + l * 8);
    float4 wb = *(const float4*)(gW2 + l * 8 + 4);
    unsigned hw[4] = {hv.x, hv.y, hv.z, hv.w};
    float wf[8] = {wa.x, wa.y, wa.z, wa.w, wb.x, wb.y, wb.z, wb.w};
    float p = 0.f;
#pragma unroll
    for (int j = 0; j < 4; ++j) {
        p += __uint_as_float(hw[j] << 16) * wf[2 * j];
        p += __uint_as_float(hw[j] & 0xffff0000u) * wf[2 * j + 1];
    }
    p = wave_sum(p);
    float gate = 1.0f / (1.0f + expf(-(p + gb2[0])));
#pragma unroll
    for (int part = 0; part < 2; ++part) {
        size_t base = (size_t)row * DDIM + part * 512 + l * 8;
        uint4 xv = *(const uint4*)(x_bf + base);
        uint4 rv = *(const uint4*)(ret2 + base);
        unsigned xw[4] = {xv.x, xv.y, xv.z, xv.w};
        unsigned rw[4] = {rv.x, rv.y, rv.z, rv.w};
        float o[8];
#pragma unroll
        for (int j = 0; j < 4; ++j) {
            o[2 * j]     = __uint_as_float(xw[j] << 16)
                         + gate * __uint_as_float(rw[j] << 16);
            o[2 * j + 1] = __uint_as_float(xw[j] & 0xffff0000u)
                         + gate * __uint_as_float(rw[j] & 0xffff0000u);
        }
        float4* po = (float4*)(out + base);
        po[0] = make_float4(o[0], o[1], o[2], o[3]);
        po[1] = make_float4(o[4], o[5], o[6], o[7]);
    }
}

extern "C" void kernel_launch(void* const* d_in, const int* in_sizes, int n_in,
                              void* d_out, int out_size, void* d_ws, size_t ws_size,
                              hipStream_t stream) {
    (void)in_sizes; (void)n_in; (void)out_size; (void)ws_size;
    const float* x   = (const float*)d_in[0];
    const float* mk  = (const float*)d_in[1];
    const float* mv  = (const float*)d_in[2];
    const float* Wq  = (const float*)d_in[3];
    const float* Wo  = (const float*)d_in[4];
    const float* gW1 = (const float*)d_in[5];
    const float* gb1 = (const float*)d_in[6];
    const float* gW2 = (const float*)d_in[7];
    const float* gb2 = (const float*)d_in[8];
    float* out = (float*)d_out;

    // workspace (~148 MB), lifetime-aliased
    char* w = (char*)d_ws;
    unsigned short* x_bf   = (unsigned short*)w;  w += (size_t)NROWS * DDIM * 2;
    unsigned short* qret   = (unsigned short*)w;  w += (size_t)NROWS * DDIM * 2;  // q then ret
    unsigned short* kn_bf  = (unsigned short*)w;  w += (size_t)SKEYS * DDIM * 2;
    unsigned short* wq_bf  = (unsigned short*)w;  w += (size_t)DDIM * DDIM * 2;
    unsigned short* wo_bf  = (unsigned short*)w;  w += (size_t)DDIM * DDIM * 2;
    unsigned short* gw1_bf = (unsigned short*)w;  w += (size_t)HDIM * 2 * DDIM * 2;
    unsigned short* sims   = (unsigned short*)w;  w += (size_t)NROWS * SKEYS * 2;  // 67 MB
    float* topw  = (float*)w;                     w += (size_t)NROWS * KTOP * 4;
    int*   topi  = (int*)w;                       w += (size_t)NROWS * KTOP * 4;
    float* qinvb = (float*)w;                     w += (size_t)NROWS * 4;
    // aliases into the dead sims region (sims dead after topk_kernel):
    unsigned short* ret2_bf = sims;                         // 33.5 MB
    unsigned short* h_bf    = sims + (size_t)NROWS * DDIM;  // 16.8 MB

    f2bf_kernel<<<2048, 256, 0, stream>>>(x,   x_bf,   NROWS * DDIM / 4);
    f2bf_kernel<<<512,  256, 0, stream>>>(Wq,  wq_bf,  DDIM * DDIM / 4);
    f2bf_kernel<<<512,  256, 0, stream>>>(Wo,  wo_bf,  DDIM * DDIM / 4);
    f2bf_kernel<<<512,  256, 0, stream>>>(gW1, gw1_bf, HDIM * 2 * DDIM / 4);
    knorm_kernel<<<SKEYS, 256, 0, stream>>>(mk, kn_bf);

    // q = x @ Wq^T -> bf16
    gemm128<0, DDIM, DDIM><<<dim3(DDIM / 128, NROWS / 128), 256, 0, stream>>>(
        x_bf, x_bf, wq_bf, nullptr, qret, DDIM);

    qinv_kernel<<<NROWS / 4, 256, 0, stream>>>(qret, qinvb);

    // sims = q @ kn^T -> bf16
    gemm128<0, DDIM, DDIM><<<dim3(SKEYS / 128, NROWS / 128), 256, 0, stream>>>(
        qret, qret, kn_bf, nullptr, sims, SKEYS);

    topk_kernel<<<NROWS / 4, 256, 0, stream>>>(sims, qinvb, topw, topi);

    retrieve_kernel<<<NROWS / 4, 256, 0, stream>>>(mv, topw, topi, qret);  // -> ret_bf

    // ret2 = ret @ Wo^T -> bf16 (into dead sims region)
    gemm128<0, DDIM, DDIM><<<dim3(DDIM / 128, NROWS / 128), 256, 0, stream>>>(
        qret, qret, wo_bf, nullptr, ret2_bf, DDIM);

    // h = gelu([x | ret2] @ gW1^T + gb1) -> bf16
    gemm128<1, DDIM, 2 * DDIM><<<dim3(HDIM / 128, NROWS / 128), 256, 0, stream>>>(
        x_bf, ret2_bf, gw1_bf, gb1, h_bf, HDIM);

    out_kernel<<<NROWS / 4, 256, 0, stream>>>(x_bf, h_bf, gW2, gb2, ret2_bf, out);
}

// Round 8
// 346.126 us; speedup vs baseline: 10.1356x; 1.1166x over previous
//
#include <hip/hip_runtime.h>
#include <math.h>

// B=4, T=4096 -> NROWS=16384; D=1024; S=2048; K=8; H=512
#define NROWS 16384
#define DDIM  1024
#define SKEYS 2048
#define KTOP  8
#define HDIM  512

typedef short  s16x8 __attribute__((ext_vector_type(8)));
typedef float  f32x4 __attribute__((ext_vector_type(4)));

#define GL16(g, l) __builtin_amdgcn_global_load_lds(                      \
    (const __attribute__((address_space(1))) void*)(g),                   \
    (__attribute__((address_space(3))) void*)(l), 16, 0, 0)

__device__ __forceinline__ float wave_sum(float v) {
#pragma unroll
    for (int off = 32; off > 0; off >>= 1) v += __shfl_xor(v, off, 64);
    return v;
}

__device__ __forceinline__ unsigned short f2bf(float f) {
    union { float f; unsigned u; } c; c.f = f;
    unsigned u = c.u;
    unsigned r = (u + 0x7FFFu + ((u >> 16) & 1u)) >> 16;
    return (unsigned short)r;
}

__device__ __forceinline__ float gelu_exact(float v) {
    return 0.5f * v * (1.0f + erff(v * 0.7071067811865475f));
}

// ---------- fp32 -> bf16 convert ----------
__global__ __launch_bounds__(256) void f2bf_kernel(const float* __restrict__ in,
                                                   unsigned short* __restrict__ out, int n4) {
    for (int i = blockIdx.x * 256 + threadIdx.x; i < n4; i += gridDim.x * 256) {
        float4 v = ((const float4*)in)[i];
        ushort4 o;
        o.x = f2bf(v.x); o.y = f2bf(v.y); o.z = f2bf(v.z); o.w = f2bf(v.w);
        ((ushort4*)out)[i] = o;
    }
}

// ---------- split gW1 [H][2D] into packed bf16 gW1a [H][D], gW1b [H][D] ----------
__global__ __launch_bounds__(256) void split_gw1_kernel(const float* __restrict__ in,
                                                        unsigned short* __restrict__ a,
                                                        unsigned short* __restrict__ b) {
    // HDIM*2*DDIM/4 = 262144 float4 groups; row = 512 groups
    for (int i = blockIdx.x * 256 + threadIdx.x; i < HDIM * 2 * DDIM / 4;
         i += gridDim.x * 256) {
        float4 v = ((const float4*)in)[i];
        int r = i >> 9;            // / (2*DDIM/4)
        int c4 = i & 511;
        ushort4 o;
        o.x = f2bf(v.x); o.y = f2bf(v.y); o.z = f2bf(v.z); o.w = f2bf(v.w);
        if (c4 < 256) ((ushort4*)a)[r * 256 + c4] = o;
        else          ((ushort4*)b)[r * 256 + (c4 - 256)] = o;
    }
}

// ---------- normalize memory_keys -> bf16 ----------
__global__ __launch_bounds__(256) void knorm_kernel(const float* __restrict__ mk,
                                                    unsigned short* __restrict__ kn) {
    int s = blockIdx.x, t = threadIdx.x;
    float4 v = ((const float4*)(mk + (size_t)s * DDIM))[t];
    float ss = v.x * v.x + v.y * v.y + v.z * v.z + v.w * v.w;
    ss = wave_sum(ss);
    __shared__ float wsum[4];
    if ((t & 63) == 0) wsum[t >> 6] = ss;
    __syncthreads();
    float tot = wsum[0] + wsum[1] + wsum[2] + wsum[3];
    float sc = 1.0f / fmaxf(sqrtf(tot), 1e-12f);
    ushort4 o;
    o.x = f2bf(v.x * sc); o.y = f2bf(v.y * sc); o.z = f2bf(v.z * sc); o.w = f2bf(v.w * sc);
    ((ushort4*)(kn + (size_t)s * DDIM))[t] = o;
}

// ---------- qinv from bf16 q ----------
__global__ __launch_bounds__(256) void qinv_kernel(const unsigned short* __restrict__ qbf,
                                                   float* __restrict__ qinv) {
    int wid = threadIdx.x >> 6, l = threadIdx.x & 63;
    int row = blockIdx.x * 4 + wid;
    const unsigned short* p = qbf + (size_t)row * DDIM + l * 16;
    uint4 a = *(const uint4*)p;
    uint4 b = *(const uint4*)(p + 8);
    float ss = 0.f;
    unsigned wsv[8] = {a.x, a.y, a.z, a.w, b.x, b.y, b.z, b.w};
#pragma unroll
    for (int j = 0; j < 8; ++j) {
        float lo = __uint_as_float(wsv[j] << 16);
        float hi = __uint_as_float(wsv[j] & 0xffff0000u);
        ss += lo * lo + hi * hi;
    }
    ss = wave_sum(ss);
    if (l == 0) qinv[row] = 1.0f / fmaxf(sqrtf(ss), 1e-12f);
}

#define INS8(v_, i_)                                                     \
    do {                                                                 \
        float insv_ = (v_); int insi_ = (i_);                            \
        _Pragma("unroll")                                                \
        for (int p_ = 0; p_ < 8; ++p_) {                                 \
            bool sw_ = insv_ > val[p_];                                  \
            float tv_ = val[p_]; int tix_ = idx[p_];                     \
            val[p_] = sw_ ? insv_ : val[p_];                             \
            idx[p_] = sw_ ? insi_ : idx[p_];                             \
            insv_ = sw_ ? tv_ : insv_; insi_ = sw_ ? tix_ : insi_;       \
        }                                                                \
    } while (0)

// ---------- 128x128 bf16 MFMA GEMM, BK=32, 4 waves, 32KB dbuf LDS ----------
// (unchanged from round 7: 2 barriers/K-tile, counted vmcnt(4), 3 blocks/CU,
//  chunk^((row>>1)&3) swizzle inverse on gload source + on ds_read)
template<int MODE, int K0, int KTOT>
__global__ __launch_bounds__(256, 3) void gemm128(
        const unsigned short* __restrict__ A0, const unsigned short* __restrict__ A1,
        const unsigned short* __restrict__ Bm, const float* __restrict__ bias,
        unsigned short* __restrict__ Cb, int Ncols) {
    __shared__ __align__(16) unsigned short As[2][4096];
    __shared__ __align__(16) unsigned short Bs[2][4096];

    int tid = threadIdx.x, l = tid & 63, wid = tid >> 6;
    int gx = gridDim.x;
    int nwg = gx * gridDim.y;
    int bid = blockIdx.y * gx + blockIdx.x;
    int cpx = nwg >> 3;
    int sbid = (bid & 7) * cpx + (bid >> 3);
    int m0 = (sbid / gx) * 128;
    int n0 = (sbid % gx) * 128;

    int wr = wid >> 1, wc = wid & 1;
    constexpr int K1 = KTOT - K0;
    constexpr int NT = KTOT >> 5;

    f32x4 acc[4][4];
#pragma unroll
    for (int i = 0; i < 4; ++i)
#pragma unroll
        for (int j = 0; j < 4; ++j) acc[i][j] = (f32x4){0.f, 0.f, 0.f, 0.f};

    int srow   = tid >> 2;
    int schunk = (tid & 3) ^ ((srow >> 1) & 3);
    int offA0[2], offA1[2], offB[2];
#pragma unroll
    for (int i = 0; i < 2; ++i) {
        int ra = m0 + i * 64 + srow;
        offA0[i] = ra * K0;
        offA1[i] = ra * K1;
        offB[i]  = (n0 + i * 64 + srow) * KTOT;
    }
    int ldsU = wid * 512;   // 1024B per wave (16 rows x 64B)

#define STAGE(bsel, kt_)                                                       \
    do {                                                                       \
        int gk_ = (kt_) * 32 + schunk * 8;                                     \
        _Pragma("unroll")                                                      \
        for (int i_ = 0; i_ < 2; ++i_) {                                       \
            const unsigned short* ga_ = (K0 == KTOT || gk_ < K0)               \
                ? A0 + offA0[i_] + gk_                                         \
                : A1 + offA1[i_] + (gk_ - K0);                                 \
            GL16(ga_, &As[bsel][i_ * 2048 + ldsU]);                            \
            GL16(Bm + offB[i_] + gk_, &Bs[bsel][i_ * 2048 + ldsU]);            \
        }                                                                      \
    } while (0)

    STAGE(0, 0);

    int frow = l & 15;
    int fp   = (l >> 4) ^ ((frow >> 1) & 3);
    int aoff = (wr * 64 + frow) * 32 + fp * 8;
    int boff = (wc * 64 + frow) * 32 + fp * 8;

#pragma unroll 2
    for (int kt = 0; kt < NT; ++kt) {
        int b = kt & 1;
        if (kt + 1 < NT) {
            STAGE(b ^ 1, kt + 1);
            asm volatile("s_waitcnt vmcnt(4)" ::: "memory");
        } else {
            asm volatile("s_waitcnt vmcnt(0)" ::: "memory");
        }
        __builtin_amdgcn_s_barrier();
        asm volatile("" ::: "memory");

        s16x8 af[4], bfr[4];
#pragma unroll
        for (int mf = 0; mf < 4; ++mf)
            af[mf] = *(const s16x8*)&As[b][aoff + mf * 512];
#pragma unroll
        for (int nf = 0; nf < 4; ++nf)
            bfr[nf] = *(const s16x8*)&Bs[b][boff + nf * 512];

        __builtin_amdgcn_s_setprio(1);
#pragma unroll
        for (int mf = 0; mf < 4; ++mf)
#pragma unroll
            for (int nf = 0; nf < 4; ++nf)
                acc[mf][nf] = __builtin_amdgcn_mfma_f32_16x16x32_bf16(
                    af[mf], bfr[nf], acc[mf][nf], 0, 0, 0);
        __builtin_amdgcn_s_setprio(0);
        asm volatile("" ::: "memory");
        __builtin_amdgcn_s_barrier();
        asm volatile("" ::: "memory");
    }
#undef STAGE

    int crow = (l >> 4) << 2;
    int ccol = l & 15;
#pragma unroll
    for (int mf = 0; mf < 4; ++mf) {
        int gr = m0 + wr * 64 + mf * 16 + crow;
#pragma unroll
        for (int nf = 0; nf < 4; ++nf) {
            int gc = n0 + wc * 64 + nf * 16 + ccol;
            f32x4 v = acc[mf][nf];
#pragma unroll
            for (int r2 = 0; r2 < 4; ++r2) {
                float o = v[r2];
                if (MODE == 1) o = gelu_exact(o + bias[gc]);
                Cb[(size_t)(gr + r2) * Ncols + gc] = f2bf(o);
            }
        }
    }
}

// ---------- top-8 + softmax from bf16 sims: one wave per row ----------
__global__ __launch_bounds__(256) void topk_kernel(
        const unsigned short* __restrict__ sims, const float* __restrict__ qinv,
        float* __restrict__ topw, int* __restrict__ topi) {
    int wid = threadIdx.x >> 6, l = threadIdx.x & 63;
    int row = blockIdx.x * 4 + wid;
    const unsigned short* sr = sims + (size_t)row * SKEYS + l * 32;
    float val[8]; int idx[8];
#pragma unroll
    for (int j = 0; j < 8; ++j) { val[j] = -1e30f; idx[j] = 0; }
#pragma unroll
    for (int c = 0; c < 4; ++c) {
        uint4 raw = *(const uint4*)(sr + c * 8);
        unsigned wsv[4] = {raw.x, raw.y, raw.z, raw.w};
#pragma unroll
        for (int q2 = 0; q2 < 4; ++q2) {
            float lo = __uint_as_float(wsv[q2] << 16);
            float hi = __uint_as_float(wsv[q2] & 0xffff0000u);
            int bi0 = l * 32 + c * 8 + q2 * 2;
            if (lo > val[7]) INS8(lo, bi0);
            if (hi > val[7]) INS8(hi, bi0 + 1);
        }
    }
    float ov[8]; int oi[8];
#pragma unroll
    for (int j = 0; j < 8; ++j) {
        float bv = val[0]; int bl = l;
#pragma unroll
        for (int off = 32; off > 0; off >>= 1) {
            float xv = __shfl_xor(bv, off, 64);
            int   xl = __shfl_xor(bl, off, 64);
            if (xv > bv || (xv == bv && xl < bl)) { bv = xv; bl = xl; }
        }
        int bi = __shfl(idx[0], bl, 64);
        ov[j] = bv; oi[j] = bi;
        if (l == bl) {
#pragma unroll
            for (int p = 0; p < 7; ++p) { val[p] = val[p + 1]; idx[p] = idx[p + 1]; }
            val[7] = -1e30f;
        }
    }
    if (l == 0) {
        float qs = qinv[row];
        float m = ov[0] * qs;
        float e[8], ssum = 0.f;
#pragma unroll
        for (int j = 0; j < 8; ++j) { e[j] = expf(ov[j] * qs - m); ssum += e[j]; }
        float inv = 1.0f / ssum;
#pragma unroll
        for (int j = 0; j < 8; ++j) {
            topw[(size_t)row * KTOP + j] = e[j] * inv;
            topi[(size_t)row * KTOP + j] = oi[j];
        }
    }
}

// ---------- fused gather + gate + residual; one wave per row ----------
// ret2 = sum_k w_k*mvo[idx_k]; h = gelu(xg1 + sum_k w_k*mvog[idx_k] + gb1);
// gate = sigmoid(h.gW2 + gb2); out = x + gate*ret2.
__global__ __launch_bounds__(256) void fused_out_kernel(
        const unsigned short* __restrict__ x_bf,
        const unsigned short* __restrict__ xg1,
        const unsigned short* __restrict__ mvo,
        const unsigned short* __restrict__ mvog,
        const float* __restrict__ topw, const int* __restrict__ topi,
        const float* __restrict__ gb1, const float* __restrict__ gW2,
        const float* __restrict__ gb2, float* __restrict__ out) {
    int wid = threadIdx.x >> 6, l = threadIdx.x & 63;
    int row = blockIdx.x * 4 + wid;
    float w[KTOP]; int id[KTOP];
#pragma unroll
    for (int k = 0; k < KTOP; ++k) {
        w[k]  = topw[(size_t)row * KTOP + k];
        id[k] = topi[(size_t)row * KTOP + k];
    }
    float r2[16], hp[8];
#pragma unroll
    for (int j = 0; j < 16; ++j) r2[j] = 0.f;
#pragma unroll
    for (int j = 0; j < 8; ++j) hp[j] = 0.f;
#pragma unroll
    for (int k = 0; k < KTOP; ++k) {
        float wk = w[k];
        const unsigned short* mo = mvo + (size_t)id[k] * DDIM + l * 16;
        uint4 a0 = *(const uint4*)mo;
        uint4 a1 = *(const uint4*)(mo + 8);
        const unsigned short* mg = mvog + (size_t)id[k] * HDIM + l * 8;
        uint4 g0 = *(const uint4*)mg;
        unsigned aw[8] = {a0.x, a0.y, a0.z, a0.w, a1.x, a1.y, a1.z, a1.w};
#pragma unroll
        for (int j = 0; j < 8; ++j) {
            r2[2 * j]     += wk * __uint_as_float(aw[j] << 16);
            r2[2 * j + 1] += wk * __uint_as_float(aw[j] & 0xffff0000u);
        }
        unsigned gw[4] = {g0.x, g0.y, g0.z, g0.w};
#pragma unroll
        for (int j = 0; j < 4; ++j) {
            hp[2 * j]     += wk * __uint_as_float(gw[j] << 16);
            hp[2 * j + 1] += wk * __uint_as_float(gw[j] & 0xffff0000u);
        }
    }
    uint4 xg = *(const uint4*)(xg1 + (size_t)row * HDIM + l * 8);
    unsigned xgw[4] = {xg.x, xg.y, xg.z, xg.w};
    float p = 0.f;
#pragma unroll
    for (int j = 0; j < 4; ++j) {
        float h0 = gelu_exact(hp[2 * j] + __uint_as_float(xgw[j] << 16)
                              + gb1[l * 8 + 2 * j]);
        float h1 = gelu_exact(hp[2 * j + 1] + __uint_as_float(xgw[j] & 0xffff0000u)
                              + gb1[l * 8 + 2 * j + 1]);
        p += h0 * gW2[l * 8 + 2 * j] + h1 * gW2[l * 8 + 2 * j + 1];
    }
    p = wave_sum(p);
    float gate = 1.0f / (1.0f + expf(-(p + gb2[0])));
    const unsigned short* xr = x_bf + (size_t)row * DDIM + l * 16;
    uint4 x0 = *(const uint4*)xr, x1 = *(const uint4*)(xr + 8);
    unsigned xw[8] = {x0.x, x0.y, x0.z, x0.w, x1.x, x1.y, x1.z, x1.w};
    float o[16];
#pragma unroll
    for (int j = 0; j < 8; ++j) {
        o[2 * j]     = __uint_as_float(xw[j] << 16)          + gate * r2[2 * j];
        o[2 * j + 1] = __uint_as_float(xw[j] & 0xffff0000u)  + gate * r2[2 * j + 1];
    }
    float4* po = (float4*)(out + (size_t)row * DDIM + l * 16);
    po[0] = make_float4(o[0], o[1], o[2], o[3]);
    po[1] = make_float4(o[4], o[5], o[6], o[7]);
    po[2] = make_float4(o[8], o[9], o[10], o[11]);
    po[3] = make_float4(o[12], o[13], o[14], o[15]);
}

extern "C" void kernel_launch(void* const* d_in, const int* in_sizes, int n_in,
                              void* d_out, int out_size, void* d_ws, size_t ws_size,
                              hipStream_t stream) {
    (void)in_sizes; (void)n_in; (void)out_size; (void)ws_size;
    const float* x   = (const float*)d_in[0];
    const float* mk  = (const float*)d_in[1];
    const float* mv  = (const float*)d_in[2];
    const float* Wq  = (const float*)d_in[3];
    const float* Wo  = (const float*)d_in[4];
    const float* gW1 = (const float*)d_in[5];
    const float* gb1 = (const float*)d_in[6];
    const float* gW2 = (const float*)d_in[7];
    const float* gb2 = (const float*)d_in[8];
    float* out = (float*)d_out;

    // workspace (~156 MB), lifetime-aliased
    char* w = (char*)d_ws;
    unsigned short* x_bf    = (unsigned short*)w;  w += (size_t)NROWS * DDIM * 2;
    unsigned short* q_bf    = (unsigned short*)w;  w += (size_t)NROWS * DDIM * 2;
    unsigned short* kn_bf   = (unsigned short*)w;  w += (size_t)SKEYS * DDIM * 2;
    unsigned short* wq_bf   = (unsigned short*)w;  w += (size_t)DDIM * DDIM * 2;
    unsigned short* wo_bf   = (unsigned short*)w;  w += (size_t)DDIM * DDIM * 2;
    unsigned short* gw1a_bf = (unsigned short*)w;  w += (size_t)HDIM * DDIM * 2;
    unsigned short* gw1b_bf = (unsigned short*)w;  w += (size_t)HDIM * DDIM * 2;
    unsigned short* mv_bf   = (unsigned short*)w;  w += (size_t)SKEYS * DDIM * 2;
    unsigned short* mvo_bf  = (unsigned short*)w;  w += (size_t)SKEYS * DDIM * 2;
    unsigned short* mvog_bf = (unsigned short*)w;  w += (size_t)SKEYS * HDIM * 2;
    unsigned short* sims    = (unsigned short*)w;  w += (size_t)NROWS * SKEYS * 2;  // 67 MB
    float* topw  = (float*)w;                      w += (size_t)NROWS * KTOP * 4;
    int*   topi  = (int*)w;                        w += (size_t)NROWS * KTOP * 4;
    float* qinvb = (float*)w;                      w += (size_t)NROWS * 4;
    unsigned short* xg1_bf = sims;  // alias: sims dead after topk (16.8 MB < 67 MB)

    f2bf_kernel<<<2048, 256, 0, stream>>>(x,  x_bf,  NROWS * DDIM / 4);
    f2bf_kernel<<<512,  256, 0, stream>>>(Wq, wq_bf, DDIM * DDIM / 4);
    f2bf_kernel<<<512,  256, 0, stream>>>(Wo, wo_bf, DDIM * DDIM / 4);
    f2bf_kernel<<<512,  256, 0, stream>>>(mv, mv_bf, SKEYS * DDIM / 4);
    split_gw1_kernel<<<1024, 256, 0, stream>>>(gW1, gw1a_bf, gw1b_bf);
    knorm_kernel<<<SKEYS, 256, 0, stream>>>(mk, kn_bf);

    // mvo = mv @ Wo^T  [S, D]
    gemm128<0, DDIM, DDIM><<<dim3(DDIM / 128, SKEYS / 128), 256, 0, stream>>>(
        mv_bf, mv_bf, wo_bf, nullptr, mvo_bf, DDIM);

    // mvog = mvo @ gW1b^T  [S, H]
    gemm128<0, DDIM, DDIM><<<dim3(HDIM / 128, SKEYS / 128), 256, 0, stream>>>(
        mvo_bf, mvo_bf, gw1b_bf, nullptr, mvog_bf, HDIM);

    // q = x @ Wq^T  [N, D]
    gemm128<0, DDIM, DDIM><<<dim3(DDIM / 128, NROWS / 128), 256, 0, stream>>>(
        x_bf, x_bf, wq_bf, nullptr, q_bf, DDIM);

    qinv_kernel<<<NROWS / 4, 256, 0, stream>>>(q_bf, qinvb);

    // sims = q @ kn^T  [N, S]
    gemm128<0, DDIM, DDIM><<<dim3(SKEYS / 128, NROWS / 128), 256, 0, stream>>>(
        q_bf, q_bf, kn_bf, nullptr, sims, SKEYS);

    topk_kernel<<<NROWS / 4, 256, 0, stream>>>(sims, qinvb, topw, topi);

    // xg1 = x @ gW1a^T  [N, H]  (into dead sims region)
    gemm128<0, DDIM, DDIM><<<dim3(HDIM / 128, NROWS / 128), 256, 0, stream>>>(
        x_bf, x_bf, gw1a_bf, nullptr, xg1_bf, HDIM);

    fused_out_kernel<<<NROWS / 4, 256, 0, stream>>>(
        x_bf, xg1_bf, mvo_bf, mvog_bf, topw, topi, gb1, gW2, gb2, out);
}

// Round 9
// 330.270 us; speedup vs baseline: 10.6223x; 1.0480x over previous
//
#include <hip/hip_runtime.h>
#include <math.h>

// B=4, T=4096 -> NROWS=16384; D=1024; S=2048; K=8; H=512
#define NROWS 16384
#define DDIM  1024
#define SKEYS 2048
#define KTOP  8
#define HDIM  512

typedef short  s16x8 __attribute__((ext_vector_type(8)));
typedef float  f32x4 __attribute__((ext_vector_type(4)));

#define GL16(g, l) __builtin_amdgcn_global_load_lds(                      \
    (const __attribute__((address_space(1))) void*)(g),                   \
    (__attribute__((address_space(3))) void*)(l), 16, 0, 0)

__device__ __forceinline__ float wave_sum(float v) {
#pragma unroll
    for (int off = 32; off > 0; off >>= 1) v += __shfl_xor(v, off, 64);
    return v;
}

__device__ __forceinline__ unsigned short f2bf(float f) {
    union { float f; unsigned u; } c; c.f = f;
    unsigned u = c.u;
    unsigned r = (u + 0x7FFFu + ((u >> 16) & 1u)) >> 16;
    return (unsigned short)r;
}

__device__ __forceinline__ float gelu_exact(float v) {
    return 0.5f * v * (1.0f + erff(v * 0.7071067811865475f));
}

__device__ __forceinline__ ushort4 cvt4(float4 v) {
    ushort4 o;
    o.x = f2bf(v.x); o.y = f2bf(v.y); o.z = f2bf(v.z); o.w = f2bf(v.w);
    return o;
}

// ---------- fused prep: knorm (block==row) + all fp32->bf16 conversions ----------
// grid MUST be SKEYS (2048) blocks x 256 threads.
__global__ __launch_bounds__(256) void prep_kernel(
        const float* __restrict__ x,   const float* __restrict__ Wq,
        const float* __restrict__ Wo,  const float* __restrict__ mv,
        const float* __restrict__ gW1, const float* __restrict__ mk,
        unsigned short* __restrict__ x_bf, unsigned short* __restrict__ wqcat,
        unsigned short* __restrict__ wo_bf, unsigned short* __restrict__ mv_bf,
        unsigned short* __restrict__ gw1b, unsigned short* __restrict__ kn) {
    int bid = blockIdx.x, t = threadIdx.x;
    // --- knorm for key row `bid` ---
    {
        float4 v = ((const float4*)(mk + (size_t)bid * DDIM))[t];
        float ss = v.x * v.x + v.y * v.y + v.z * v.z + v.w * v.w;
        ss = wave_sum(ss);
        __shared__ float wsum[4];
        if ((t & 63) == 0) wsum[t >> 6] = ss;
        __syncthreads();
        float tot = wsum[0] + wsum[1] + wsum[2] + wsum[3];
        float sc = 1.0f / fmaxf(sqrtf(tot), 1e-12f);
        float4 o = make_float4(v.x * sc, v.y * sc, v.z * sc, v.w * sc);
        ((ushort4*)(kn + (size_t)bid * DDIM))[t] = cvt4(o);
    }
    int gid = bid * 256 + t, stride = gridDim.x * 256;
    // --- x -> x_bf ---
    for (int i = gid; i < NROWS * DDIM / 4; i += stride)
        ((ushort4*)x_bf)[i] = cvt4(((const float4*)x)[i]);
    // --- Wq -> wqcat rows [0,1024) ---
    for (int i = gid; i < DDIM * DDIM / 4; i += stride)
        ((ushort4*)wqcat)[i] = cvt4(((const float4*)Wq)[i]);
    // --- gW1 split: a -> wqcat rows [1024,1536), b -> gw1b ---
    for (int i = gid; i < HDIM * 2 * DDIM / 4; i += stride) {
        float4 v = ((const float4*)gW1)[i];
        int r = i >> 9, c4 = i & 511;
        if (c4 < 256) ((ushort4*)wqcat)[DDIM * DDIM / 4 + r * 256 + c4] = cvt4(v);
        else          ((ushort4*)gw1b)[r * 256 + (c4 - 256)] = cvt4(v);
    }
    // --- Wo -> wo_bf ---
    for (int i = gid; i < DDIM * DDIM / 4; i += stride)
        ((ushort4*)wo_bf)[i] = cvt4(((const float4*)Wo)[i]);
    // --- mv -> mv_bf ---
    for (int i = gid; i < SKEYS * DDIM / 4; i += stride)
        ((ushort4*)mv_bf)[i] = cvt4(((const float4*)mv)[i]);
}

// ---------- qinv from bf16 q ----------
__global__ __launch_bounds__(256) void qinv_kernel(const unsigned short* __restrict__ qbf,
                                                   float* __restrict__ qinv) {
    int wid = threadIdx.x >> 6, l = threadIdx.x & 63;
    int row = blockIdx.x * 4 + wid;
    const unsigned short* p = qbf + (size_t)row * DDIM + l * 16;
    uint4 a = *(const uint4*)p;
    uint4 b = *(const uint4*)(p + 8);
    float ss = 0.f;
    unsigned wsv[8] = {a.x, a.y, a.z, a.w, b.x, b.y, b.z, b.w};
#pragma unroll
    for (int j = 0; j < 8; ++j) {
        float lo = __uint_as_float(wsv[j] << 16);
        float hi = __uint_as_float(wsv[j] & 0xffff0000u);
        ss += lo * lo + hi * hi;
    }
    ss = wave_sum(ss);
    if (l == 0) qinv[row] = 1.0f / fmaxf(sqrtf(ss), 1e-12f);
}

#define INS8(v_, i_)                                                     \
    do {                                                                 \
        float insv_ = (v_); int insi_ = (i_);                            \
        _Pragma("unroll")                                                \
        for (int p_ = 0; p_ < 8; ++p_) {                                 \
            bool sw_ = insv_ > val[p_];                                  \
            float tv_ = val[p_]; int tix_ = idx[p_];                     \
            val[p_] = sw_ ? insv_ : val[p_];                             \
            idx[p_] = sw_ ? insi_ : idx[p_];                             \
            insv_ = sw_ ? tv_ : insv_; insi_ = sw_ ? tix_ : insi_;       \
        }                                                                \
    } while (0)

// ---------- 128x128 bf16 MFMA GEMM, BK=32, 4 waves, 32KB dbuf LDS ----------
// MODE 0: C -> bf16.  MODE 2: split output, blocks with n0>=nsplit write C2.
// (proven round-7 structure: 2 barriers/K-tile, counted vmcnt(4),
//  chunk^((row>>1)&3) swizzle inverse on gload source + on ds_read)
template<int MODE, int K0, int KTOT>
__global__ __launch_bounds__(256, 3) void gemm128(
        const unsigned short* __restrict__ A0, const unsigned short* __restrict__ A1,
        const unsigned short* __restrict__ Bm, const float* __restrict__ bias,
        unsigned short* __restrict__ Cb, int Ncols,
        unsigned short* __restrict__ C2, int N2cols, int nsplit) {
    __shared__ __align__(16) unsigned short As[2][4096];
    __shared__ __align__(16) unsigned short Bs[2][4096];

    int tid = threadIdx.x, l = tid & 63, wid = tid >> 6;
    int gx = gridDim.x;
    int nwg = gx * gridDim.y;
    int bid = blockIdx.y * gx + blockIdx.x;
    int cpx = nwg >> 3;
    int sbid = (bid & 7) * cpx + (bid >> 3);
    int m0 = (sbid / gx) * 128;
    int n0 = (sbid % gx) * 128;

    int wr = wid >> 1, wc = wid & 1;
    constexpr int K1 = KTOT - K0;
    constexpr int NT = KTOT >> 5;

    f32x4 acc[4][4];
#pragma unroll
    for (int i = 0; i < 4; ++i)
#pragma unroll
        for (int j = 0; j < 4; ++j) acc[i][j] = (f32x4){0.f, 0.f, 0.f, 0.f};

    int srow   = tid >> 2;
    int schunk = (tid & 3) ^ ((srow >> 1) & 3);
    int offA0[2], offA1[2], offB[2];
#pragma unroll
    for (int i = 0; i < 2; ++i) {
        int ra = m0 + i * 64 + srow;
        offA0[i] = ra * K0;
        offA1[i] = ra * K1;
        offB[i]  = (n0 + i * 64 + srow) * KTOT;
    }
    int ldsU = wid * 512;   // 1024B per wave (16 rows x 64B)

#define STAGE(bsel, kt_)                                                       \
    do {                                                                       \
        int gk_ = (kt_) * 32 + schunk * 8;                                     \
        _Pragma("unroll")                                                      \
        for (int i_ = 0; i_ < 2; ++i_) {                                       \
            const unsigned short* ga_ = (K0 == KTOT || gk_ < K0)               \
                ? A0 + offA0[i_] + gk_                                         \
                : A1 + offA1[i_] + (gk_ - K0);                                 \
            GL16(ga_, &As[bsel][i_ * 2048 + ldsU]);                            \
            GL16(Bm + offB[i_] + gk_, &Bs[bsel][i_ * 2048 + ldsU]);            \
        }                                                                      \
    } while (0)

    STAGE(0, 0);

    int frow = l & 15;
    int fp   = (l >> 4) ^ ((frow >> 1) & 3);
    int aoff = (wr * 64 + frow) * 32 + fp * 8;
    int boff = (wc * 64 + frow) * 32 + fp * 8;

#pragma unroll 2
    for (int kt = 0; kt < NT; ++kt) {
        int b = kt & 1;
        if (kt + 1 < NT) {
            STAGE(b ^ 1, kt + 1);
            asm volatile("s_waitcnt vmcnt(4)" ::: "memory");
        } else {
            asm volatile("s_waitcnt vmcnt(0)" ::: "memory");
        }
        __builtin_amdgcn_s_barrier();
        asm volatile("" ::: "memory");

        s16x8 af[4], bfr[4];
#pragma unroll
        for (int mf = 0; mf < 4; ++mf)
            af[mf] = *(const s16x8*)&As[b][aoff + mf * 512];
#pragma unroll
        for (int nf = 0; nf < 4; ++nf)
            bfr[nf] = *(const s16x8*)&Bs[b][boff + nf * 512];

        __builtin_amdgcn_s_setprio(1);
#pragma unroll
        for (int mf = 0; mf < 4; ++mf)
#pragma unroll
            for (int nf = 0; nf < 4; ++nf)
                acc[mf][nf] = __builtin_amdgcn_mfma_f32_16x16x32_bf16(
                    af[mf], bfr[nf], acc[mf][nf], 0, 0, 0);
        __builtin_amdgcn_s_setprio(0);
        asm volatile("" ::: "memory");
        __builtin_amdgcn_s_barrier();
        asm volatile("" ::: "memory");
    }
#undef STAGE

    // output routing (block-uniform)
    unsigned short* cptr = Cb;
    int nc = Ncols, cb = n0;
    if (MODE == 2 && n0 >= nsplit) { cptr = C2; nc = N2cols; cb = n0 - nsplit; }

    int crow = (l >> 4) << 2;
    int ccol = l & 15;
#pragma unroll
    for (int mf = 0; mf < 4; ++mf) {
        int gr = m0 + wr * 64 + mf * 16 + crow;
#pragma unroll
        for (int nf = 0; nf < 4; ++nf) {
            int gc = cb + wc * 64 + nf * 16 + ccol;
            f32x4 v = acc[mf][nf];
#pragma unroll
            for (int r2 = 0; r2 < 4; ++r2) {
                float o = v[r2];
                cptr[(size_t)(gr + r2) * nc + gc] = f2bf(o);
            }
        }
    }
    (void)bias;
}

// ---------- top-8 + softmax from bf16 sims: one wave per row ----------
__global__ __launch_bounds__(256) void topk_kernel(
        const unsigned short* __restrict__ sims, const float* __restrict__ qinv,
        float* __restrict__ topw, int* __restrict__ topi) {
    int wid = threadIdx.x >> 6, l = threadIdx.x & 63;
    int row = blockIdx.x * 4 + wid;
    const unsigned short* sr = sims + (size_t)row * SKEYS + l * 32;
    float val[8]; int idx[8];
#pragma unroll
    for (int j = 0; j < 8; ++j) { val[j] = -1e30f; idx[j] = 0; }
#pragma unroll
    for (int c = 0; c < 4; ++c) {
        uint4 raw = *(const uint4*)(sr + c * 8);
        unsigned wsv[4] = {raw.x, raw.y, raw.z, raw.w};
#pragma unroll
        for (int q2 = 0; q2 < 4; ++q2) {
            float lo = __uint_as_float(wsv[q2] << 16);
            float hi = __uint_as_float(wsv[q2] & 0xffff0000u);
            int bi0 = l * 32 + c * 8 + q2 * 2;
            if (lo > val[7]) INS8(lo, bi0);
            if (hi > val[7]) INS8(hi, bi0 + 1);
        }
    }
    float ov[8]; int oi[8];
#pragma unroll
    for (int j = 0; j < 8; ++j) {
        float bv = val[0]; int bl = l;
#pragma unroll
        for (int off = 32; off > 0; off >>= 1) {
            float xv = __shfl_xor(bv, off, 64);
            int   xl = __shfl_xor(bl, off, 64);
            if (xv > bv || (xv == bv && xl < bl)) { bv = xv; bl = xl; }
        }
        int bi = __shfl(idx[0], bl, 64);
        ov[j] = bv; oi[j] = bi;
        if (l == bl) {
#pragma unroll
            for (int p = 0; p < 7; ++p) { val[p] = val[p + 1]; idx[p] = idx[p + 1]; }
            val[7] = -1e30f;
        }
    }
    if (l == 0) {
        float qs = qinv[row];
        float m = ov[0] * qs;
        float e[8], ssum = 0.f;
#pragma unroll
        for (int j = 0; j < 8; ++j) { e[j] = expf(ov[j] * qs - m); ssum += e[j]; }
        float inv = 1.0f / ssum;
#pragma unroll
        for (int j = 0; j < 8; ++j) {
            topw[(size_t)row * KTOP + j] = e[j] * inv;
            topi[(size_t)row * KTOP + j] = oi[j];
        }
    }
}

// ---------- fused gather + gate + residual; one wave per row ----------
__global__ __launch_bounds__(256) void fused_out_kernel(
        const unsigned short* __restrict__ x_bf,
        const unsigned short* __restrict__ xg1,
        const unsigned short* __restrict__ mvo,
        const unsigned short* __restrict__ mvog,
        const float* __restrict__ topw, const int* __restrict__ topi,
        const float* __restrict__ gb1, const float* __restrict__ gW2,
        const float* __restrict__ gb2, float* __restrict__ out) {
    int wid = threadIdx.x >> 6, l = threadIdx.x & 63;
    int row = blockIdx.x * 4 + wid;
    float w[KTOP]; int id[KTOP];
#pragma unroll
    for (int k = 0; k < KTOP; ++k) {
        w[k]  = topw[(size_t)row * KTOP + k];
        id[k] = topi[(size_t)row * KTOP + k];
    }
    float r2[16], hp[8];
#pragma unroll
    for (int j = 0; j < 16; ++j) r2[j] = 0.f;
#pragma unroll
    for (int j = 0; j < 8; ++j) hp[j] = 0.f;
#pragma unroll
    for (int k = 0; k < KTOP; ++k) {
        float wk = w[k];
        const unsigned short* mo = mvo + (size_t)id[k] * DDIM + l * 16;
        uint4 a0 = *(const uint4*)mo;
        uint4 a1 = *(const uint4*)(mo + 8);
        const unsigned short* mg = mvog + (size_t)id[k] * HDIM + l * 8;
        uint4 g0 = *(const uint4*)mg;
        unsigned aw[8] = {a0.x, a0.y, a0.z, a0.w, a1.x, a1.y, a1.z, a1.w};
#pragma unroll
        for (int j = 0; j < 8; ++j) {
            r2[2 * j]     += wk * __uint_as_float(aw[j] << 16);
            r2[2 * j + 1] += wk * __uint_as_float(aw[j] & 0xffff0000u);
        }
        unsigned gw[4] = {g0.x, g0.y, g0.z, g0.w};
#pragma unroll
        for (int j = 0; j < 4; ++j) {
            hp[2 * j]     += wk * __uint_as_float(gw[j] << 16);
            hp[2 * j + 1] += wk * __uint_as_float(gw[j] & 0xffff0000u);
        }
    }
    uint4 xg = *(const uint4*)(xg1 + (size_t)row * HDIM + l * 8);
    unsigned xgw[4] = {xg.x, xg.y, xg.z, xg.w};
    float p = 0.f;
#pragma unroll
    for (int j = 0; j < 4; ++j) {
        float h0 = gelu_exact(hp[2 * j] + __uint_as_float(xgw[j] << 16)
                              + gb1[l * 8 + 2 * j]);
        float h1 = gelu_exact(hp[2 * j + 1] + __uint_as_float(xgw[j] & 0xffff0000u)
                              + gb1[l * 8 + 2 * j + 1]);
        p += h0 * gW2[l * 8 + 2 * j] + h1 * gW2[l * 8 + 2 * j + 1];
    }
    p = wave_sum(p);
    float gate = 1.0f / (1.0f + expf(-(p + gb2[0])));
    const unsigned short* xr = x_bf + (size_t)row * DDIM + l * 16;
    uint4 x0 = *(const uint4*)xr, x1 = *(const uint4*)(xr + 8);
    unsigned xw[8] = {x0.x, x0.y, x0.z, x0.w, x1.x, x1.y, x1.z, x1.w};
    float o[16];
#pragma unroll
    for (int j = 0; j < 8; ++j) {
        o[2 * j]     = __uint_as_float(xw[j] << 16)          + gate * r2[2 * j];
        o[2 * j + 1] = __uint_as_float(xw[j] & 0xffff0000u)  + gate * r2[2 * j + 1];
    }
    float4* po = (float4*)(out + (size_t)row * DDIM + l * 16);
    po[0] = make_float4(o[0], o[1], o[2], o[3]);
    po[1] = make_float4(o[4], o[5], o[6], o[7]);
    po[2] = make_float4(o[8], o[9], o[10], o[11]);
    po[3] = make_float4(o[12], o[13], o[14], o[15]);
}

extern "C" void kernel_launch(void* const* d_in, const int* in_sizes, int n_in,
                              void* d_out, int out_size, void* d_ws, size_t ws_size,
                              hipStream_t stream) {
    (void)in_sizes; (void)n_in; (void)out_size; (void)ws_size;
    const float* x   = (const float*)d_in[0];
    const float* mk  = (const float*)d_in[1];
    const float* mv  = (const float*)d_in[2];
    const float* Wq  = (const float*)d_in[3];
    const float* Wo  = (const float*)d_in[4];
    const float* gW1 = (const float*)d_in[5];
    const float* gb1 = (const float*)d_in[6];
    const float* gW2 = (const float*)d_in[7];
    const float* gb2 = (const float*)d_in[8];
    float* out = (float*)d_out;

    // workspace (~172 MB), lifetime-aliased
    char* w = (char*)d_ws;
    unsigned short* x_bf    = (unsigned short*)w;  w += (size_t)NROWS * DDIM * 2;        // 33.5
    unsigned short* q_bf    = (unsigned short*)w;  w += (size_t)NROWS * DDIM * 2;        // 33.5
    unsigned short* xg1_bf  = (unsigned short*)w;  w += (size_t)NROWS * HDIM * 2;        // 16.8
    unsigned short* kn_bf   = (unsigned short*)w;  w += (size_t)SKEYS * DDIM * 2;        // 4.2
    unsigned short* wqcat   = (unsigned short*)w;  w += (size_t)(DDIM + HDIM) * DDIM * 2;// 3.1 [Wq;gW1a]
    unsigned short* gw1b_bf = (unsigned short*)w;  w += (size_t)HDIM * DDIM * 2;         // 1.0
    unsigned short* wo_bf   = (unsigned short*)w;  w += (size_t)DDIM * DDIM * 2;         // 2.1
    unsigned short* mv_bf   = (unsigned short*)w;  w += (size_t)SKEYS * DDIM * 2;        // 4.2
    unsigned short* mvo_bf  = (unsigned short*)w;  w += (size_t)SKEYS * DDIM * 2;        // 4.2
    unsigned short* mvog_bf = (unsigned short*)w;  w += (size_t)SKEYS * HDIM * 2;        // 2.1
    unsigned short* sims    = (unsigned short*)w;  w += (size_t)NROWS * SKEYS * 2;       // 67
    float* topw  = (float*)w;                      w += (size_t)NROWS * KTOP * 4;
    int*   topi  = (int*)w;                        w += (size_t)NROWS * KTOP * 4;
    float* qinvb = (float*)w;                      w += (size_t)NROWS * 4;

    // 1. all conversions + knorm, one launch
    prep_kernel<<<SKEYS, 256, 0, stream>>>(x, Wq, Wo, mv, gW1, mk,
                                           x_bf, wqcat, wo_bf, mv_bf, gw1b_bf, kn_bf);

    // 2. mvo = mv @ Wo^T  [S, D]
    gemm128<0, DDIM, DDIM><<<dim3(DDIM / 128, SKEYS / 128), 256, 0, stream>>>(
        mv_bf, mv_bf, wo_bf, nullptr, mvo_bf, DDIM, nullptr, 0, 0);

    // 3. mvog = mvo @ gW1b^T  [S, H]
    gemm128<0, DDIM, DDIM><<<dim3(HDIM / 128, SKEYS / 128), 256, 0, stream>>>(
        mvo_bf, mvo_bf, gw1b_bf, nullptr, mvog_bf, HDIM, nullptr, 0, 0);

    // 4. [q | xg1] = x @ [Wq ; gW1a]^T  [N, 1536] split at col 1024
    gemm128<2, DDIM, DDIM><<<dim3((DDIM + HDIM) / 128, NROWS / 128), 256, 0, stream>>>(
        x_bf, x_bf, wqcat, nullptr, q_bf, DDIM, xg1_bf, HDIM, DDIM);

    // 5. qinv
    qinv_kernel<<<NROWS / 4, 256, 0, stream>>>(q_bf, qinvb);

    // 6. sims = q @ kn^T  [N, S]
    gemm128<0, DDIM, DDIM><<<dim3(SKEYS / 128, NROWS / 128), 256, 0, stream>>>(
        q_bf, q_bf, kn_bf, nullptr, sims, SKEYS, nullptr, 0, 0);

    // 7. top-8 + softmax
    topk_kernel<<<NROWS / 4, 256, 0, stream>>>(sims, qinvb, topw, topi);

    // 8. gather + gate + residual
    fused_out_kernel<<<NROWS / 4, 256, 0, stream>>>(
        x_bf, xg1_bf, mvo_bf, mvog_bf, topw, topi, gb1, gW2, gb2, out);
}